// Round 7
// baseline (690.612 us; speedup 1.0000x reference)
//
#include <hip/hip_runtime.h>
#include <math.h>

#ifndef M_PI
#define M_PI 3.14159265358979323846
#endif

#define NGRID 513
#define NCELL 512
#define NINT  511
#define NB    4

constexpr int N2G = NGRID * NGRID;   // 263169
constexpr int NI2 = NINT * NINT;     // 261121
constexpr int NQ  = 257 * 257;       // 66049 (rh antisym quadrant)

// GEMM LDS row stride (ushorts). 42 = 84B = 21 banks; gcd(21,32)=1 so a
// quad's 16 lanes hit 16 distinct base banks (2-lane minimum aliasing,
// free per G4). Was 40 (20 banks, gcd 4) -> 2.7M conflict cycles/dispatch.
#define LDSW 42

typedef unsigned short ushort;
typedef unsigned int uint32;
typedef __attribute__((ext_vector_type(8))) short short8;
typedef __attribute__((ext_vector_type(8))) unsigned short ushort8;
typedef __attribute__((ext_vector_type(4))) float f32x4;

// ---------------------------------------------------------------------------
// bf16 split helpers (RNE)
// ---------------------------------------------------------------------------
__device__ __forceinline__ ushort f2bf(float x) {
    unsigned u = __float_as_uint(x);
    unsigned r = u + 0x7FFFu + ((u >> 16) & 1u);
    return (ushort)(r >> 16);
}
__device__ __forceinline__ float bf2f(ushort h) {
    return __uint_as_float(((unsigned)h) << 16);
}

// rh antisymmetric-quadrant read: rq = batch base (257x257), (i,j) full-grid.
__device__ __forceinline__ float rhq_read(const float* __restrict__ rq,
                                          int i, int j) {
    float s = 1.0f;
    if (i > 256) { i = 512 - i; s = -s; }
    if (j > 256) { j = 512 - j; s = -s; }
    return s * rq[i * 257 + j];
}

// wt * ik2 complex scale (bitwise-identical to the original k_scale expression)
__device__ __forceinline__ float2 scale_wt(float x0, float x1, float wr, float wi,
                                           int gr, int gc) {
    int du = gr - 256, dv = gc - 256;
    float ik2;
    if (du == 0 && dv == 0)
        ik2 = 1.0f;
    else
        ik2 = (float)(1.0 / (9.869604401089358 * (double)(du * du + dv * dv)));
    return make_float2((x0 * wr - x1 * wi) * ik2, (x0 * wi + x1 * wr) * ik2);
}

// ---------------------------------------------------------------------------
// FEM Darcy operator at interior node (i,j), i,j in 1..511
// ---------------------------------------------------------------------------
__device__ __forceinline__ float darcyA(const float* __restrict__ x,
                                        const float* __restrict__ a,
                                        int i, int j) {
    const float c23 = 2.0f / 3.0f, c16 = 1.0f / 6.0f, c13 = 1.0f / 3.0f;
    float a00 = a[(i - 1) * NCELL + (j - 1)];
    float a01 = a[(i - 1) * NCELL + j];
    float a10 = a[i * NCELL + (j - 1)];
    float a11 = a[i * NCELL + j];
    const float* xm = x + (i - 1) * NGRID;
    const float* xc = x + i * NGRID;
    const float* xp = x + (i + 1) * NGRID;
    return c23 * (a00 + a01 + a10 + a11) * xc[j]
         - c16 * ((a00 + a01) * xm[j] + (a10 + a11) * xp[j]
                + (a00 + a10) * xc[j - 1] + (a01 + a11) * xc[j + 1])
         - c13 * (a00 * xm[j - 1] + a01 * xm[j + 1]
                + a10 * xp[j - 1] + a11 * xp[j + 1]);
}

// ---------------------------------------------------------------------------
// R20: 5 fused weighted-Jacobi sweeps per launch (validated).
// RES=1 additionally emits r = f - A x5 + transposed bf16 gemm1-B planes.
// ---------------------------------------------------------------------------
template <int RES>
__global__ __launch_bounds__(256) void k_jacobi5R(
    const float* __restrict__ xin, const float* __restrict__ a,
    const float* __restrict__ f, const float* __restrict__ dinv,
    float* __restrict__ out, float* __restrict__ rout,
    ushort* __restrict__ tBh, ushort* __restrict__ tBl) {
    constexpr int H  = RES ? 6 : 5;
    constexpr int SX = 16 + 2 * H;        // 28 / 26
    constexpr int SA = SX - 1;            // 27 / 25
    constexpr int SF = 16 + 2 * (H - 1);  // 26 / 24
    __shared__ float sx[SX][SX];
    __shared__ float sa[SA][SA + 1];
    __shared__ float sf[SF][SF];
    __shared__ float sd[SF][SF];
    __shared__ float sp[2][SF][SF + 2];
    __shared__ float st[16][17];
    const float c23 = 2.0f / 3.0f, c16 = 1.0f / 6.0f, c13 = 1.0f / 3.0f;
    int b = blockIdx.z;
    const float* xb = xin + (long long)b * N2G;
    const float* ab = a + (long long)b * NCELL * NCELL;
    const float* fb = f + (long long)b * N2G;
    const float* db = dinv + (long long)b * NI2;
    int ox = blockIdx.x * 16, oy = blockIdx.y * 16;
    int tx = threadIdx.x, ty = threadIdx.y;
    int tid = ty * 16 + tx;

    for (int idx = tid; idx < SX * SX; idx += 256) {
        int ly = idx / SX, lx = idx % SX;
        int gy = oy - H + ly, gx = ox - H + lx;
        bool in = (gy >= 0 && gy < NGRID && gx >= 0 && gx < NGRID);
        sx[ly][lx] = in ? xb[(long long)gy * NGRID + gx] : 0.0f;
    }
    for (int idx = tid; idx < SA * SA; idx += 256) {
        int ly = idx / SA, lx = idx % SA;
        int gy = oy - H + ly, gx = ox - H + lx;
        bool in = (gy >= 0 && gy < NCELL && gx >= 0 && gx < NCELL);
        sa[ly][lx] = in ? ab[(long long)gy * NCELL + gx] : 0.0f;
    }
    for (int idx = tid; idx < SF * SF; idx += 256) {
        int ly = idx / SF, lx = idx % SF;
        int gy = oy - (H - 1) + ly, gx = ox - (H - 1) + lx;
        bool ing = (gy >= 0 && gy < NGRID && gx >= 0 && gx < NGRID);
        bool itr = (gy >= 1 && gy <= NINT && gx >= 1 && gx <= NINT);
        sf[ly][lx] = ing ? fb[(long long)gy * NGRID + gx] : 0.0f;
        sd[ly][lx] = itr ? db[(long long)(gy - 1) * NINT + (gx - 1)] : 0.0f;
    }
    __syncthreads();

    for (int idx = tid; idx < SF * SF; idx += 256) {
        int ly = idx / SF, lx = idx % SF;
        int gy = oy - (H - 1) + ly, gx = ox - (H - 1) + lx;
        float v = 0.0f;
        if (gy >= 0 && gy < NGRID && gx >= 0 && gx < NGRID) {
            float xc = sx[ly + 1][lx + 1];
            if (gy >= 1 && gy <= NINT && gx >= 1 && gx <= NINT) {
                float a00 = sa[ly][lx], a01 = sa[ly][lx + 1];
                float a10 = sa[ly + 1][lx], a11 = sa[ly + 1][lx + 1];
                float Ax = c23 * (a00 + a01 + a10 + a11) * xc
                    - c16 * ((a00 + a01) * sx[ly][lx + 1] + (a10 + a11) * sx[ly + 2][lx + 1]
                           + (a00 + a10) * sx[ly + 1][lx] + (a01 + a11) * sx[ly + 1][lx + 2])
                    - c13 * (a00 * sx[ly][lx] + a01 * sx[ly][lx + 2]
                           + a10 * sx[ly + 2][lx] + a11 * sx[ly + 2][lx + 2]);
                v = xc + 0.75f * sd[ly][lx] * (sf[ly][lx] - Ax);
            } else {
                v = xc;
            }
        }
        sp[0][ly][lx] = v;
    }
    __syncthreads();

    #pragma unroll 1
    for (int s = 2; s <= 5; ++s) {
        int sz = 16 + 2 * (H - s);
        int cur = (s - 1) & 1, prv = s & 1;
        for (int idx = tid; idx < sz * sz; idx += 256) {
            int ly = idx / sz, lx = idx % sz;
            int gy = oy - (H - s) + ly, gx = ox - (H - s) + lx;
            float v = 0.0f;
            if (gy >= 0 && gy < NGRID && gx >= 0 && gx < NGRID) {
                float xc = sp[prv][ly + 1][lx + 1];
                if (gy >= 1 && gy <= NINT && gx >= 1 && gx <= NINT) {
                    int ar = ly + s - 1, ac = lx + s - 1;
                    float a00 = sa[ar][ac], a01 = sa[ar][ac + 1];
                    float a10 = sa[ar + 1][ac], a11 = sa[ar + 1][ac + 1];
                    float Ax = c23 * (a00 + a01 + a10 + a11) * xc
                        - c16 * ((a00 + a01) * sp[prv][ly][lx + 1] + (a10 + a11) * sp[prv][ly + 2][lx + 1]
                               + (a00 + a10) * sp[prv][ly + 1][lx] + (a01 + a11) * sp[prv][ly + 1][lx + 2])
                        - c13 * (a00 * sp[prv][ly][lx] + a01 * sp[prv][ly][lx + 2]
                               + a10 * sp[prv][ly + 2][lx] + a11 * sp[prv][ly + 2][lx + 2]);
                    int fr = ly + s - 1, fc = lx + s - 1;
                    v = xc + 0.75f * sd[fr][fc] * (sf[fr][fc] - Ax);
                } else {
                    v = xc;
                }
            }
            sp[cur][ly][lx] = v;
        }
        __syncthreads();
    }

    int gy = oy + ty, gx = ox + tx;
    long long gidx = (long long)b * N2G + (long long)gy * NGRID + gx;
    if constexpr (!RES) {
        if (gy < NGRID && gx < NGRID) out[gidx] = sp[0][ty][tx];
    } else {
        float rv = 0.0f;
        if (gy < NGRID && gx < NGRID) {
            float x5 = sp[0][ty + 1][tx + 1];
            out[gidx] = x5;
            if (gy >= 1 && gy <= NINT && gx >= 1 && gx <= NINT) {
                float a00 = sa[ty + 5][tx + 5], a01 = sa[ty + 5][tx + 6];
                float a10 = sa[ty + 6][tx + 5], a11 = sa[ty + 6][tx + 6];
                float Ax = c23 * (a00 + a01 + a10 + a11) * x5
                    - c16 * ((a00 + a01) * sp[0][ty][tx + 1] + (a10 + a11) * sp[0][ty + 2][tx + 1]
                           + (a00 + a10) * sp[0][ty + 1][tx] + (a01 + a11) * sp[0][ty + 1][tx + 2])
                    - c13 * (a00 * sp[0][ty][tx] + a01 * sp[0][ty][tx + 2]
                           + a10 * sp[0][ty + 2][tx] + a11 * sp[0][ty + 2][tx + 2]);
                rv = sf[ty + 5][tx + 5] - Ax;
            } else {
                rv = sf[ty + 5][tx + 5];
            }
            rout[gidx] = rv;
        }
        st[ty][tx] = rv;
        __syncthreads();
        int i2 = blockIdx.y * 16 + tx;   // = k+1
        int j2 = blockIdx.x * 16 + ty;   // = n+1
        if (i2 >= 1 && i2 <= NINT && j2 >= 1 && j2 <= NINT) {
            float r2 = st[tx][ty];
            ushort h = f2bf(r2);
            long long o = (long long)b * 511 * 512
                        + (long long)(j2 - 1) * 512 + (i2 - 1);
            tBh[o] = h;
            tBl[o] = f2bf(r2 - bf2f(h));
        }
    }
}

// ---------------------------------------------------------------------------
// R21: trig tables (3074 distinct double sin/cos values; expressions
// identical to the originals -> downstream bits unchanged).
// ---------------------------------------------------------------------------
__global__ void k_tables(double* __restrict__ tabD, double* __restrict__ tabC,
                         double* __restrict__ tabS) {
    int t = blockIdx.x * 256 + threadIdx.x;
    if (t < 1024) tabD[t] = sin((M_PI / 512.0) * (double)t);
    if (t < 1025) {
        double ang = (2.0 * M_PI / 1025.0) * (double)t;
        tabC[t] = cos(ang);
        tabS[t] = sin(ang);
    }
}

__device__ __forceinline__ void wsplit(double v, ushort* Dh, ushort* Dl,
                                       long long idx) {
    float vf = (float)v;
    ushort h = f2bf(vf);
    Dh[idx] = h;
    Dl[idx] = f2bf(vf - bf2f(h));
}

// R21: all static bf16 matrices + dinv in ONE kernel (region-partitioned).
constexpr long long R_DSTA = 513LL * 512;       // 262656
constexpr long long R_DSTB = 513LL * 512;       // 262656
constexpr long long R_FA   = 511LL * 1056;      // 539616
constexpr long long R_FB   = 1022LL * 1056;     // 1079232
constexpr long long R_DINV = (long long)NB * NI2; // 1044484
constexpr long long R_TOT  = R_DSTA + R_DSTB + R_FA + R_FB + R_DINV;

__global__ void k_genAll(const double* __restrict__ tabD,
                         const double* __restrict__ tabC,
                         const double* __restrict__ tabS,
                         const float* __restrict__ coef,
                         float* __restrict__ dinv,
                         ushort* __restrict__ GAh, ushort* __restrict__ GAl,
                         ushort* __restrict__ GBh, ushort* __restrict__ GBl,
                         ushort* __restrict__ FAh, ushort* __restrict__ FAl,
                         ushort* __restrict__ FBh, ushort* __restrict__ FBl) {
    long long gid = (long long)blockIdx.x * 256 + threadIdx.x;
    if (gid < R_DSTA) {  // DST A: sin(pi t/512)
        int idx = (int)gid;
        int u = idx / 512, k = idx % 512;
        double v = 0.0;
        if (k < 511) {
            int t = ((u - 256) * (k + 1)) % 1024;
            if (t < 0) t += 1024;
            v = tabD[t];
        }
        wsplit(v, GAh, GAl, idx);
        return;
    }
    gid -= R_DSTA;
    if (gid < R_DSTB) {  // DST B^T scaled
        int idx = (int)gid;
        int v2 = idx / 512, k = idx % 512;
        double val = 0.0;
        if (k < 511) {
            int t = ((v2 - 256) * (k + 1)) % 1024;
            if (t < 0) t += 1024;
            val = tabD[t] * (-1.0 / 262144.0);
        }
        wsplit(val, GBh, GBl, idx);
        return;
    }
    gid -= R_DSTB;
    if (gid < R_FA) {    // F A (511 x 1056)
        int idx = (int)gid;
        int y = idx / 1056, k = idx % 1056;
        double v = 0.0;
        if (k < 1026) {
            int m = (k < 513) ? k : (k - 513);
            long t = ((long)y * (m - 255)) % 1025;
            if (t < 0) t += 1025;
            v = (k < 513) ? tabC[t] : -tabS[t];
        }
        wsplit(v, FAh, FAl, idx);
        return;
    }
    gid -= R_FA;
    if (gid < R_FB) {    // F B (1022 x 1056)
        int idx = (int)gid;
        int n = idx / 1056, k = idx % 1056;
        double v = 0.0;
        if (k < 1026) {
            int m = (k < 513) ? k : (k - 513);
            int y = (n < 511) ? n : (n - 511);
            long t = ((long)y * (m - 255)) % 1025;
            if (t < 0) t += 1025;
            bool ktop = (k < 513), nleft = (n < 511);
            if (ktop && nleft)        v = tabC[t];
            else if (ktop && !nleft)  v = -tabS[t];
            else if (!ktop && nleft)  v = tabS[t];
            else                      v = tabC[t];
        }
        wsplit(v, FBh, FBl, idx);
        return;
    }
    gid -= R_FB;
    if (gid < R_DINV) {  // dinv
        long long idx = gid;
        int b = (int)(idx / NI2);
        int rem = (int)(idx % NI2);
        int p = rem / NINT, q = rem % NINT;
        const float* ab = coef + (long long)b * NCELL * NCELL;
        float s = ab[p * NCELL + q] + ab[p * NCELL + q + 1]
                + ab[(p + 1) * NCELL + q] + ab[(p + 1) * NCELL + q + 1];
        dinv[idx] = 1.0f / ((2.0f / 3.0f) * s);
    }
}

// ---------------------------------------------------------------------------
// Fused split-K reduce + bf16 convert (GEMM->GEMM handoffs).
// ---------------------------------------------------------------------------
__global__ void k_redA(const float* __restrict__ P, int nsplit, int Mr,
                       ushort* __restrict__ Dh, ushort* __restrict__ Dl) {
    int b = blockIdx.y;
    int idx = blockIdx.x * 256 + threadIdx.x;
    if (idx >= Mr * 512) return;
    int m = idx / 512, k = idx % 512;
    float v = 0.0f;
    if (k < 511) {
        long long base = (long long)m * 511 + k;
        long long str = (long long)Mr * 511;
        #pragma unroll 4
        for (int s = 0; s < nsplit; ++s)
            v += P[((long long)b * nsplit + s) * str + base];
    }
    long long o = (long long)b * Mr * 512 + idx;
    ushort h = f2bf(v);
    Dh[o] = h;
    Dl[o] = f2bf(v - bf2f(h));
}

__global__ void k_redBt(const float* __restrict__ P, int nsplit,
                        ushort* __restrict__ Dh, ushort* __restrict__ Dl) {
    int b = blockIdx.y;
    int idx = blockIdx.x * 256 + threadIdx.x;
    if (idx >= 511 * 1056) return;
    int n = idx / 1056, k = idx % 1056;
    float v = 0.0f;
    if (k < 1026) {
        int row = (k < 513) ? n : (511 + n);
        int col = (k < 513) ? k : (k - 513);
        long long base = (long long)row * 513 + col;
        float acc = 0.0f;
        #pragma unroll 4
        for (int s = 0; s < nsplit; ++s)
            acc += P[((long long)b * nsplit + s) * (1022LL * 513) + base];
        v = (k < 513) ? acc : -acc;
    }
    long long o = (long long)b * 511 * 1056 + idx;
    ushort h = f2bf(v);
    Dh[o] = h;
    Dl[o] = f2bf(v - bf2f(h));
}

// ---------------------------------------------------------------------------
// MFMA real GEMM, 3-term split-bf16 (hh + hl + lh), 16x16x32 bf16 MFMA.
// R23: LDS row stride 40 -> 42 ushorts (bank-conflict fix, see LDSW).
// ---------------------------------------------------------------------------
__global__ __launch_bounds__(256) void k_mgemm(
    const ushort* __restrict__ Ah, const ushort* __restrict__ Al, long long bsA,
    const ushort* __restrict__ Bh, const ushort* __restrict__ Bl, long long bsB,
    float* __restrict__ C, long long bsC,
    int M, int N, int Kp, int nsplit) {
    __shared__ ushort sAh[128 * LDSW];
    __shared__ ushort sAl[128 * LDSW];
    __shared__ ushort sBh[128 * LDSW];
    __shared__ ushort sBl[128 * LDSW];

    int bz = blockIdx.z, b = bz / nsplit, ks = bz % nsplit;
    int kchunk = (((Kp + nsplit - 1) / nsplit) + 31) & ~31;
    int kbeg = ks * kchunk;
    int kend = min(Kp, kbeg + kchunk);

    Ah += b * bsA; Al += b * bsA;
    Bh += b * bsB; Bl += b * bsB;
    C += ((long long)b * nsplit + ks) * bsC;

    int bm = blockIdx.y * 128, bn = blockIdx.x * 128;
    int tid = threadIdx.x;
    int wave = tid >> 6, lane = tid & 63;
    int wm = (wave >> 1) * 64, wn = (wave & 1) * 64;
    int quad = lane >> 4, l16 = lane & 15;

    f32x4 zf = {0.f, 0.f, 0.f, 0.f};
    f32x4 acc[4][4];
    #pragma unroll
    for (int i = 0; i < 4; ++i)
        #pragma unroll
        for (int j = 0; j < 4; ++j) acc[i][j] = zf;

    int srow = tid >> 2;
    int sk8 = (tid & 3) * 8;

    for (int kt = kbeg; kt < kend; kt += 32) {
        #pragma unroll
        for (int h = 0; h < 2; ++h) {
            int row = srow + 64 * h;
            ushort8 vh = {0, 0, 0, 0, 0, 0, 0, 0};
            ushort8 vl = {0, 0, 0, 0, 0, 0, 0, 0};
            int gm = bm + row;
            if (gm < M) {
                vh = *(const ushort8*)(Ah + (long long)gm * Kp + kt + sk8);
                vl = *(const ushort8*)(Al + (long long)gm * Kp + kt + sk8);
            }
            *(ushort8*)(sAh + row * LDSW + sk8) = vh;
            *(ushort8*)(sAl + row * LDSW + sk8) = vl;
            ushort8 wh = {0, 0, 0, 0, 0, 0, 0, 0};
            ushort8 wl = {0, 0, 0, 0, 0, 0, 0, 0};
            int gn = bn + row;
            if (gn < N) {
                wh = *(const ushort8*)(Bh + (long long)gn * Kp + kt + sk8);
                wl = *(const ushort8*)(Bl + (long long)gn * Kp + kt + sk8);
            }
            *(ushort8*)(sBh + row * LDSW + sk8) = wh;
            *(ushort8*)(sBl + row * LDSW + sk8) = wl;
        }
        __syncthreads();

        short8 afh[4], afl[4], bfh[4], bfl[4];
        #pragma unroll
        for (int t = 0; t < 4; ++t) {
            int ar = wm + t * 16 + l16;
            afh[t] = *(const short8*)(sAh + ar * LDSW + quad * 8);
            afl[t] = *(const short8*)(sAl + ar * LDSW + quad * 8);
            int br = wn + t * 16 + l16;
            bfh[t] = *(const short8*)(sBh + br * LDSW + quad * 8);
            bfl[t] = *(const short8*)(sBl + br * LDSW + quad * 8);
        }
        #pragma unroll
        for (int mt = 0; mt < 4; ++mt)
            #pragma unroll
            for (int nt = 0; nt < 4; ++nt) {
                acc[mt][nt] = __builtin_amdgcn_mfma_f32_16x16x32_bf16(
                    afh[mt], bfh[nt], acc[mt][nt], 0, 0, 0);
                acc[mt][nt] = __builtin_amdgcn_mfma_f32_16x16x32_bf16(
                    afh[mt], bfl[nt], acc[mt][nt], 0, 0, 0);
                acc[mt][nt] = __builtin_amdgcn_mfma_f32_16x16x32_bf16(
                    afl[mt], bfh[nt], acc[mt][nt], 0, 0, 0);
            }
        __syncthreads();
    }

    #pragma unroll
    for (int mt = 0; mt < 4; ++mt) {
        #pragma unroll
        for (int r = 0; r < 4; ++r) {
            int gm = bm + wm + mt * 16 + quad * 4 + r;
            if (gm >= M) continue;
            long long rowoff = (long long)gm * N;
            #pragma unroll
            for (int nt = 0; nt < 4; ++nt) {
                int gn = bn + wn + nt * 16 + l16;
                if (gn < N) C[rowoff + gn] = acc[mt][nt][r];
            }
        }
    }
}

// ---------------------------------------------------------------------------
// Sum nsplit dense [M x N] partials -> strided fp32 output (row stride ldo).
// ---------------------------------------------------------------------------
__global__ void k_reduce(const float* __restrict__ Pr,
                         float* __restrict__ outR,
                         int MN, int N, int ldo, long long bsOut, int nsplit) {
    int b = blockIdx.y;
    for (int idx = blockIdx.x * 256 + threadIdx.x; idx < MN;
         idx += gridDim.x * 256) {
        float sr = 0.0f;
        #pragma unroll 4
        for (int s = 0; s < nsplit; ++s)
            sr += Pr[((long long)b * nsplit + s) * MN + idx];
        int m = idx / N, n = idx - m * N;
        outR[(long long)b * bsOut + (long long)m * ldo + n] = sr;
    }
}

// ---------------------------------------------------------------------------
// Composed conv-chain (validated R17): each 3-conv chain == one complex 7x7.
// ---------------------------------------------------------------------------
__device__ __forceinline__ float2 cmul(float2 a, float2 b) {
    return make_float2(a.x * b.x - a.y * b.y, a.x * b.y + a.y * b.x);
}

__global__ void k_compose(const float* __restrict__ w1r, const float* __restrict__ w1i,
                          const float* __restrict__ w2r, const float* __restrict__ w2i,
                          const float* __restrict__ w3r, const float* __restrict__ w3i,
                          float* __restrict__ kc) {
    int chain = blockIdx.x, b = blockIdx.y;
    int tid = threadIdx.x;  // 128
    __shared__ float2 sW1[4][9], sW2[16][9], sW3[4][9], sW21[4][25];
    for (int idx = tid; idx < 36; idx += 128) {
        int c = idx / 9, s = idx % 9, p = s / 3, q = s % 3;
        if (chain == 0) {
            int i1 = b * 36 + c * 9 + p * 3 + q;
            sW1[c][s] = make_float2(w1r[i1], w1i[i1]);
            sW3[c][s] = make_float2(w3r[i1], w3i[i1]);
        } else {
            int it = b * 36 + c * 9 + q * 3 + p;
            sW1[c][s] = make_float2(w3r[it], -w3i[it]);
            sW3[c][s] = make_float2(w1r[it], -w1i[it]);
        }
    }
    for (int idx = tid; idx < 144; idx += 128) {
        int co = idx / 36, r = idx % 36, ci = r / 9, s = r % 9, p = s / 3, q = s % 3;
        int iw = (chain == 0) ? (b * 144 + co * 36 + ci * 9 + p * 3 + q)
                              : (b * 144 + ci * 36 + co * 9 + q * 3 + p);
        float iv = w2i[iw];
        sW2[co * 4 + ci][s] = make_float2(w2r[iw], (chain == 0) ? iv : -iv);
    }
    __syncthreads();
    for (int idx = tid; idx < 100; idx += 128) {
        int cm = idx / 25, r = idx % 25, di = r / 5 - 2, dj = r % 5 - 2;
        float2 acc = make_float2(0.f, 0.f);
        for (int c1 = 0; c1 < 4; ++c1)
            for (int p = 0; p < 3; ++p)
                for (int q = 0; q < 3; ++q) {
                    int ei = di - (p - 1) + 1, ej = dj - (q - 1) + 1;
                    if (ei >= 0 && ei < 3 && ej >= 0 && ej < 3) {
                        float2 t = cmul(sW2[cm * 4 + c1][p * 3 + q], sW1[c1][ei * 3 + ej]);
                        acc.x += t.x; acc.y += t.y;
                    }
                }
        sW21[cm][r] = acc;
    }
    __syncthreads();
    for (int idx = tid; idx < 49; idx += 128) {
        int di = idx / 7 - 3, dj = idx % 7 - 3;
        float2 acc = make_float2(0.f, 0.f);
        for (int cm = 0; cm < 4; ++cm)
            for (int p = 0; p < 3; ++p)
                for (int q = 0; q < 3; ++q) {
                    int ei = di - (p - 1), ej = dj - (q - 1);
                    if (ei >= -2 && ei <= 2 && ej >= -2 && ej <= 2) {
                        float2 t = cmul(sW3[cm][p * 3 + q], sW21[cm][(ei + 2) * 5 + (ej + 2)]);
                        acc.x += t.x; acc.y += t.y;
                    }
                }
        ((float2*)kc)[(b * 2 + chain) * 49 + idx] = acc;
    }
}

// main composed 7x7 conv (R19 re-tile: 16x32 output tile, 2 rows/thread).
template <int MODE>
__global__ __launch_bounds__(256) void k_conv7(
    const float* __restrict__ xr, const float* __restrict__ xi,
    const float* __restrict__ wtr, const float* __restrict__ wti,
    const float* __restrict__ kc,
    float* __restrict__ outr, float* __restrict__ outi,
    ushort* __restrict__ oAh, ushort* __restrict__ oAl) {
    constexpr bool CPLX = (MODE == 1);
    __shared__ float2 tile[38][23];
    __shared__ float2 kt[49];
    int b = blockIdx.z;
    int tid = threadIdx.y * 16 + threadIdx.x;
    const float2* kb = (const float2*)kc + (b * 2 + MODE) * 49;
    for (int idx = tid; idx < 49; idx += 256) kt[idx] = kb[idx];
    int row_base = blockIdx.y * 32 - 3;
    int col_base = blockIdx.x * 16 - 3;
    const float* rq = xr + (long long)b * NQ;
    for (int idx = tid; idx < 38 * 22; idx += 256) {
        int r = idx / 22, c = idx % 22;
        int gr = row_base + r, gc = col_base + c;
        float vr = 0.0f, vi = 0.0f;
        if (gr >= 0 && gr < NGRID && gc >= 0 && gc < NGRID) {
            if (MODE == 0) {
                vr = rhq_read(rq, gr, gc);
            } else {
                long long g = (long long)b * N2G + (long long)gr * NGRID + gc;
                float2 sc = scale_wt(xr[g], xi[g], wtr[g], wti[g], gr, gc);
                vr = sc.x; vi = sc.y;
            }
        }
        tile[r][c] = make_float2(vr, vi);
    }
    __syncthreads();

    int tx = threadIdx.x, r0 = threadIdx.y * 2;
    float2 acc[2];
    acc[0] = make_float2(0.f, 0.f);
    acc[1] = make_float2(0.f, 0.f);
    #pragma unroll
    for (int t = 0; t < 7; ++t) {
        float2 kv[7];
        #pragma unroll
        for (int s = 0; s < 7; ++s) kv[s] = kt[s * 7 + t];
        #pragma unroll
        for (int rr = 0; rr < 8; ++rr) {
            float2 xv = tile[r0 + rr][tx + t];
            #pragma unroll
            for (int s = 0; s < 7; ++s) {
                int orow = rr - s;
                if (orow >= 0 && orow < 2) {
                    acc[orow].x += kv[s].x * xv.x;
                    acc[orow].y += kv[s].y * xv.x;
                    if (CPLX) {
                        acc[orow].x -= kv[s].y * xv.y;
                        acc[orow].y += kv[s].x * xv.y;
                    }
                }
            }
        }
    }
    int gc = blockIdx.x * 16 + tx;
    if (gc >= NGRID) return;
    #pragma unroll
    for (int r = 0; r < 2; ++r) {
        int gr = blockIdx.y * 32 + r0 + r;
        if (gr < NGRID) {
            if (MODE == 0) {
                long long g = (long long)b * N2G + (long long)gr * NGRID + gc;
                outr[g] = acc[r].x;
                outi[g] = acc[r].y;
            } else {
                long long o = (long long)b * 513 * 1056
                            + (long long)gr * 1056 + gc;
                ushort h = f2bf(acc[r].x);
                oAh[o] = h;
                oAl[o] = f2bf(acc[r].x - bf2f(h));
                ushort h2 = f2bf(acc[r].y);
                oAh[o + 513] = h2;
                oAl[o + 513] = f2bf(acc[r].y - bf2f(h2));
            }
        }
    }
}

// exact sequential recompute of the width-2 border ring (validated R4).
template <int CHAIN>
__global__ __launch_bounds__(256) void k_ring7(
    const float* __restrict__ xr, const float* __restrict__ xi,
    const float* __restrict__ wtr, const float* __restrict__ wti,
    const float* __restrict__ w1r, const float* __restrict__ w1i,
    const float* __restrict__ w2r, const float* __restrict__ w2i,
    const float* __restrict__ w3r, const float* __restrict__ w3i,
    float* __restrict__ outr, float* __restrict__ outi,
    ushort* __restrict__ oAh, ushort* __restrict__ oAl) {
    constexpr bool CPLX = (CHAIN == 1);
    __shared__ float2 W1s[4][9], W2s[16][9], W3s[4][9];
    __shared__ float2 Y[4][4][68];
    __shared__ float2 Z[4][3][66];
    int side = blockIdx.y, b = blockIdx.z;
    int u0 = blockIdx.x * 64;
    int ulo = (side < 2) ? 0 : 2;
    int uhi = (side < 2) ? (NGRID - 1) : (NGRID - 3);
    if (u0 > uhi) return;
    int tid = threadIdx.x;
    const float* rq = xr + (long long)b * NQ;

    for (int idx = tid; idx < 36; idx += 256) {
        int c = idx / 9, s = idx % 9, p = s / 3, q = s % 3;
        if (CHAIN == 0) {
            int i1 = b * 36 + c * 9 + p * 3 + q;
            W1s[c][s] = make_float2(w1r[i1], w1i[i1]);
            W3s[c][s] = make_float2(w3r[i1], w3i[i1]);
        } else {
            int it = b * 36 + c * 9 + q * 3 + p;
            W1s[c][s] = make_float2(w3r[it], -w3i[it]);
            W3s[c][s] = make_float2(w1r[it], -w1i[it]);
        }
    }
    for (int idx = tid; idx < 144; idx += 256) {
        int co = idx / 36, r = idx % 36, ci = r / 9, s = r % 9, p = s / 3, q = s % 3;
        int iw = (CHAIN == 0) ? (b * 144 + co * 36 + ci * 9 + p * 3 + q)
                              : (b * 144 + ci * 36 + co * 9 + q * 3 + p);
        float iv = w2i[iw];
        W2s[co * 4 + ci][s] = make_float2(w2r[iw], (CHAIN == 0) ? iv : -iv);
    }
    __syncthreads();

    for (int idx = tid; idx < 4 * 4 * 68; idx += 256) {
        int ch = idx / (4 * 68), r = idx % (4 * 68), d = r / 68, uu = r % 68;
        int u = u0 - 2 + uu;
        float2 acc = make_float2(0.f, 0.f);
        if (u >= 0 && u < NGRID) {
            int i, j;
            if (side == 0)      { i = d;       j = u; }
            else if (side == 1) { i = 512 - d; j = u; }
            else if (side == 2) { i = u;       j = d; }
            else                { i = u;       j = 512 - d; }
            for (int p = 0; p < 3; ++p)
                for (int q = 0; q < 3; ++q) {
                    int ii = i + p - 1, jj = j + q - 1;
                    if (ii >= 0 && ii < NGRID && jj >= 0 && jj < NGRID) {
                        float vr, vi;
                        if (CHAIN == 0) {
                            vr = rhq_read(rq, ii, jj);
                            vi = 0.0f;
                        } else {
                            long long g = (long long)b * N2G
                                        + (long long)ii * NGRID + jj;
                            float2 sc = scale_wt(xr[g], xi[g], wtr[g], wti[g],
                                                 ii, jj);
                            vr = sc.x; vi = sc.y;
                        }
                        float2 w = W1s[ch][p * 3 + q];
                        acc.x += w.x * vr - w.y * vi;
                        acc.y += w.x * vi + w.y * vr;
                    }
                }
        }
        Y[ch][d][uu] = acc;
    }
    __syncthreads();

    for (int idx = tid; idx < 4 * 3 * 66; idx += 256) {
        int co = idx / (3 * 66), r = idx % (3 * 66), d = r / 66, uu = r % 66;
        int u = u0 - 1 + uu;
        float2 acc = make_float2(0.f, 0.f);
        if (u >= 0 && u < NGRID) {
            for (int p = 0; p < 3; ++p)
                for (int q = 0; q < 3; ++q) {
                    int dd, du;
                    if (side == 0)      { dd = p - 1; du = q - 1; }
                    else if (side == 1) { dd = 1 - p; du = q - 1; }
                    else if (side == 2) { dd = q - 1; du = p - 1; }
                    else                { dd = 1 - q; du = p - 1; }
                    int d2 = d + dd, uy = uu + 1 + du;
                    if (d2 >= 0) {
                        for (int ci = 0; ci < 4; ++ci) {
                            float2 yv = Y[ci][d2][uy];
                            float2 w = W2s[co * 4 + ci][p * 3 + q];
                            acc.x += w.x * yv.x - w.y * yv.y;
                            acc.y += w.x * yv.y + w.y * yv.x;
                        }
                    }
                }
        }
        Z[co][d][uu] = acc;
    }
    __syncthreads();

    for (int idx = tid; idx < 128; idx += 256) {
        int d = idx / 64, uu = idx % 64;
        int u = u0 + uu;
        if (u < ulo || u > uhi) continue;
        float2 acc = make_float2(0.f, 0.f);
        for (int p = 0; p < 3; ++p)
            for (int q = 0; q < 3; ++q) {
                int dd, du;
                if (side == 0)      { dd = p - 1; du = q - 1; }
                else if (side == 1) { dd = 1 - p; du = q - 1; }
                else if (side == 2) { dd = q - 1; du = p - 1; }
                else                { dd = 1 - q; du = p - 1; }
                int d2 = d + dd, uz = uu + 1 + du;
                if (d2 >= 0) {
                    for (int ci = 0; ci < 4; ++ci) {
                        float2 zv = Z[ci][d2][uz];
                        float2 w = W3s[ci][p * 3 + q];
                        acc.x += w.x * zv.x - w.y * zv.y;
                        acc.y += w.x * zv.y + w.y * zv.x;
                    }
                }
            }
        int i, j;
        if (side == 0)      { i = d;       j = u; }
        else if (side == 1) { i = 512 - d; j = u; }
        else if (side == 2) { i = u;       j = d; }
        else                { i = u;       j = 512 - d; }
        if (CHAIN == 0) {
            long long g = (long long)b * N2G + (long long)i * NGRID + j;
            outr[g] = acc.x;
            outi[g] = acc.y;
        } else {
            long long o = (long long)b * 513 * 1056 + (long long)i * 1056 + j;
            ushort h = f2bf(acc.x);
            oAh[o] = h;
            oAl[o] = f2bf(acc.x - bf2f(h));
            ushort h2 = f2bf(acc.y);
            oAh[o + 513] = h2;
            oAl[o + 513] = f2bf(acc.y - bf2f(h2));
        }
    }
}

// ---------------------------------------------------------------------------
// red[2b] += sum(r*e), red[2b+1] += sum((A e)*e), Ae computed inline.
// ---------------------------------------------------------------------------
__global__ void k_dotAe(const float* __restrict__ r, const float* __restrict__ e,
                        const float* __restrict__ a, float* __restrict__ red) {
    int b = blockIdx.y;
    const float* rb = r + (long long)b * N2G;
    const float* eb = e + (long long)b * N2G;
    const float* ab = a + (long long)b * NCELL * NCELL;
    float s1 = 0.0f, s2 = 0.0f;
    for (int idx = blockIdx.x * blockDim.x + threadIdx.x; idx < NI2;
         idx += gridDim.x * blockDim.x) {
        int i = idx / NINT + 1, j = idx % NINT + 1;
        long long g = (long long)i * NGRID + j;
        float ev = eb[g];
        float Ax = darcyA(eb, ab, i, j);
        s1 += rb[g] * ev;
        s2 += Ax * ev;
    }
    #pragma unroll
    for (int o = 32; o > 0; o >>= 1) {
        s1 += __shfl_down(s1, o);
        s2 += __shfl_down(s2, o);
    }
    __shared__ float l1[4], l2[4];
    int wid = threadIdx.x >> 6;
    if ((threadIdx.x & 63) == 0) { l1[wid] = s1; l2[wid] = s2; }
    __syncthreads();
    if (threadIdx.x == 0) {
        atomicAdd(&red[2 * b], l1[0] + l1[1] + l1[2] + l1[3]);
        atomicAdd(&red[2 * b + 1], l2[0] + l2[1] + l2[2] + l2[3]);
    }
}

__global__ void k_update(float* __restrict__ x, const float* __restrict__ e,
                         const float* __restrict__ red) {
    long long idx = (long long)blockIdx.x * blockDim.x + threadIdx.x;
    if (idx >= (long long)NB * N2G) return;
    int b = (int)(idx / N2G);
    float alpha = red[2 * b] / red[2 * b + 1];
    x[idx] += alpha * e[idx];
}

// ---------------------------------------------------------------------------
// final: r = f - A(x + alpha e) fused with norm accumulation.
// ---------------------------------------------------------------------------
__global__ void k_fin(const float* __restrict__ x, const float* __restrict__ e,
                      const float* __restrict__ f, const float* __restrict__ a,
                      float* __restrict__ red) {
    const float c23 = 2.0f / 3.0f, c16 = 1.0f / 6.0f, c13 = 1.0f / 3.0f;
    int b = blockIdx.y;
    long long base = (long long)b * N2G;
    const float* ab = a + (long long)b * NCELL * NCELL;
    float alpha = red[8 + 2 * b] / red[8 + 2 * b + 1];
    float s1 = 0.0f, s2 = 0.0f;
    for (int idx = blockIdx.x * blockDim.x + threadIdx.x; idx < N2G;
         idx += gridDim.x * blockDim.x) {
        int i = idx / NGRID, j = idx - i * NGRID;
        float fv = f[base + idx];
        float rv = fv;
        if (i >= 1 && i <= NINT && j >= 1 && j <= NINT) {
            float a00 = ab[(i - 1) * NCELL + (j - 1)];
            float a01 = ab[(i - 1) * NCELL + j];
            float a10 = ab[i * NCELL + (j - 1)];
            float a11 = ab[i * NCELL + j];
            long long gm = base + (long long)(i - 1) * NGRID + j;
            long long gc = base + (long long)i * NGRID + j;
            long long gp = base + (long long)(i + 1) * NGRID + j;
            float xmm = x[gm - 1] + alpha * e[gm - 1];
            float xm0 = x[gm] + alpha * e[gm];
            float xmp = x[gm + 1] + alpha * e[gm + 1];
            float xcm = x[gc - 1] + alpha * e[gc - 1];
            float xc0 = x[gc] + alpha * e[gc];
            float xcp = x[gc + 1] + alpha * e[gc + 1];
            float xpm = x[gp - 1] + alpha * e[gp - 1];
            float xp0 = x[gp] + alpha * e[gp];
            float xpp = x[gp + 1] + alpha * e[gp + 1];
            float Ax = c23 * (a00 + a01 + a10 + a11) * xc0
                - c16 * ((a00 + a01) * xm0 + (a10 + a11) * xp0
                       + (a00 + a10) * xcm + (a01 + a11) * xcp)
                - c13 * (a00 * xmm + a01 * xmp + a10 * xpm + a11 * xpp);
            rv = fv - Ax;
        }
        s1 += rv * rv;
        s2 += fv * fv;
    }
    #pragma unroll
    for (int o = 32; o > 0; o >>= 1) {
        s1 += __shfl_down(s1, o);
        s2 += __shfl_down(s2, o);
    }
    __shared__ float l1[4], l2[4];
    int wid = threadIdx.x >> 6;
    if ((threadIdx.x & 63) == 0) { l1[wid] = s1; l2[wid] = s2; }
    __syncthreads();
    if (threadIdx.x == 0) {
        atomicAdd(&red[16], l1[0] + l1[1] + l1[2] + l1[3]);
        atomicAdd(&red[17], l2[0] + l2[1] + l2[2] + l2[3]);
    }
}

__global__ void k_final(const float* __restrict__ red, float* __restrict__ out) {
    out[0] = sqrtf(red[16] / red[17]);
}

// ---------------------------------------------------------------------------
extern "C" void kernel_launch(void* const* d_in, const int* in_sizes, int n_in,
                              void* d_out, int out_size, void* d_ws, size_t ws_size,
                              hipStream_t stream) {
    (void)in_sizes; (void)n_in; (void)out_size; (void)ws_size;
    const float* f    = (const float*)d_in[0];
    const float* coef = (const float*)d_in[1];
    const float* w1r  = (const float*)d_in[3];
    const float* w1i  = (const float*)d_in[4];
    const float* w2r  = (const float*)d_in[5];
    const float* w2i  = (const float*)d_in[6];
    const float* w3r  = (const float*)d_in[7];
    const float* w3i  = (const float*)d_in[8];
    const float* wtr  = (const float*)d_in[9];
    const float* wti  = (const float*)d_in[10];
    float* out = (float*)d_out;

    float* ws = (float*)d_ws;
    size_t off = 0;
    auto alloc = [&](long long n) {
        float* p = ws + off;
        off += (size_t)((n + 3) & ~3LL);
        return p;
    };
    float* x0   = alloc((long long)NB * N2G);
    float* x1   = alloc((long long)NB * N2G);
    float* rr   = alloc((long long)NB * N2G);
    float* ee   = alloc((long long)NB * N2G);
    float* dinv = alloc((long long)NB * NI2);
    float* c1r  = alloc((long long)NB * 4 * N2G);
    float* c1i  = alloc((long long)NB * 4 * N2G);
    float* c2r  = alloc((long long)NB * 4 * N2G);
    float* c2i  = alloc((long long)NB * 4 * N2G);
    float* pr   = c1r;  // partial span (c1r..c2i contiguous, ~67 MB)
    float* or_  = alloc((long long)NB * N2G);
    float* oi_  = alloc((long long)NB * N2G);
    float* rhq  = alloc((long long)NB * NQ);   // rh antisym quadrant 257x257
    float* red  = alloc(20);
    ushort* sGh  = (ushort*)alloc(513 * 512 / 2);
    ushort* sGl  = (ushort*)alloc(513 * 512 / 2);
    ushort* sGth = (ushort*)alloc(513 * 512 / 2);
    ushort* sGtl = (ushort*)alloc(513 * 512 / 2);
    ushort* sFAh = (ushort*)alloc(511 * 1056 / 2);
    ushort* sFAl = (ushort*)alloc(511 * 1056 / 2);
    ushort* sFBh = (ushort*)alloc(1022 * 1056 / 2);
    ushort* sFBl = (ushort*)alloc(1022 * 1056 / 2);
    ushort* dA2h = (ushort*)alloc((long long)NB * 257 * 512 / 2);  // gemm2 A
    ushort* dA2l = (ushort*)alloc((long long)NB * 257 * 512 / 2);
    ushort* dA3h = (ushort*)alloc((long long)NB * 513 * 1056 / 2); // gemm3 B
    ushort* dA3l = (ushort*)alloc((long long)NB * 513 * 1056 / 2);
    ushort* dB1h = (ushort*)alloc((long long)NB * 511 * 512 / 2);  // gemm1 B
    ushort* dB1l = (ushort*)alloc((long long)NB * 511 * 512 / 2);
    ushort* dB4h = (ushort*)alloc((long long)NB * 511 * 1056 / 2); // gemm4 B
    ushort* dB4l = (ushort*)alloc((long long)NB * 511 * 1056 / 2);
    float* kcomp = alloc(NB * 2 * 49 * 2);   // composed 7x7 chain kernels
    double* tabD = (double*)alloc(1024 * 2); // sin(pi t/512), t<1024
    double* tabC = (double*)alloc(1026 * 2); // cos(2pi t/1025), t<1025
    double* tabS = (double*)alloc(1026 * 2); // sin(2pi t/1025), t<1025

    dim3 blk2(16, 16);
    dim3 grdS(33, 33, NB);
    dim3 grdC(33, 17, NB);   // conv7: 16x32 output tile per block (R19)
    dim3 grdR(9, 4, NB);     // ring7: 64-wide segments x 4 sides
    const int SP = 4;

    hipMemsetAsync(x0, 0, (size_t)NB * N2G * sizeof(float), stream);
    hipMemsetAsync(ee, 0, (size_t)NB * N2G * sizeof(float), stream);
    hipMemsetAsync(red, 0, 20 * sizeof(float), stream);
    hipMemsetAsync(dA3h, 0, (size_t)NB * 513 * 1056 * 2 * 2, stream);
    hipMemsetAsync(dB1h, 0, (size_t)NB * 511 * 512 * 2 * 2, stream);
    k_tables<<<dim3(5), dim3(256), 0, stream>>>(tabD, tabC, tabS);
    k_genAll<<<dim3((unsigned)((R_TOT + 255) / 256)), dim3(256), 0, stream>>>(
        tabD, tabC, tabS, coef, dinv,
        sGh, sGl, sGth, sGtl, sFAh, sFAl, sFBh, sFBl);
    k_compose<<<dim3(2, NB), dim3(128), 0, stream>>>(w1r, w1i, w2r, w2i, w3r, w3i, kcomp);

    for (int step = 0; step < 2; ++step) {
        // 10 weighted-Jacobi sweeps: x0 -> x1 (5), x1 -> x0 (5 + residual +
        // bf16 transpose planes for gemm1 B)
        k_jacobi5R<0><<<grdS, blk2, 0, stream>>>(
            x0, coef, f, dinv, x1, nullptr, nullptr, nullptr);
        k_jacobi5R<1><<<grdS, blk2, 0, stream>>>(
            x1, coef, f, dinv, x0, rr, dB1h, dB1l);

        // ---- H_apply ----
        // gemm1: t2 = G(257x511) * rI(511x511)   [antisym: M 513 -> 257]
        k_mgemm<<<dim3(4, 3, NB * SP), dim3(256), 0, stream>>>(
            sGh, sGl, 0, dB1h, dB1l, (long long)511 * 512,
            pr, (long long)257 * 511, 257, 511, 512, SP);
        k_redA<<<dim3((257 * 512 + 255) / 256, NB), dim3(256), 0, stream>>>(
            pr, SP, 257, dA2h, dA2l);
        // gemm2: rh_q = t2(257x511) * Gt(511x257) [antisym: N 513 -> 257]
        k_mgemm<<<dim3(3, 3, NB * SP), dim3(256), 0, stream>>>(
            dA2h, dA2l, (long long)257 * 512, sGth, sGtl, 0,
            pr, (long long)NQ, 257, 257, 512, SP);
        k_reduce<<<dim3(259, NB), dim3(256), 0, stream>>>(
            pr, rhq, NQ, 257, 257, (long long)NQ, SP);

        // forward conv chain (rh mirror-read) -> or_/oi_
        k_conv7<0><<<grdC, blk2, 0, stream>>>(
            rhq, nullptr, nullptr, nullptr, kcomp, or_, oi_, nullptr, nullptr);
        k_ring7<0><<<grdR, dim3(256), 0, stream>>>(
            rhq, nullptr, nullptr, nullptr,
            w1r, w1i, w2r, w2i, w3r, w3i, or_, oi_, nullptr, nullptr);
        // adjoint conv chain (fused wt*ik2 scale on load) -> bf16 dA3 planes
        k_conv7<1><<<grdC, blk2, 0, stream>>>(
            or_, oi_, wtr, wti, kcomp, nullptr, nullptr, dA3h, dA3l);
        k_ring7<1><<<grdR, dim3(256), 0, stream>>>(
            or_, oi_, wtr, wti,
            w1r, w1i, w2r, w2i, w3r, w3i, nullptr, nullptr, dA3h, dA3l);

        // gemm3' (transposed): P'[n<1022][m<513] = sFB * dA3^T
        k_mgemm<<<dim3(5, 8, NB * 4), dim3(256), 0, stream>>>(
            sFBh, sFBl, 0, dA3h, dA3l, (long long)513 * 1056,
            pr, 1022LL * 513, 1022, 513, 1056, 4);
        k_redBt<<<dim3(2109, NB), dim3(256), 0, stream>>>(pr, 4, dB4h, dB4l);
        // gemm4: e = [Fr|Fi](511x1026) * [t2r;-t2i](1026x511)
        k_mgemm<<<dim3(4, 4, NB * SP), dim3(256), 0, stream>>>(
            sFAh, sFAl, 0, dB4h, dB4l, (long long)511 * 1056,
            pr, (long long)NI2, 511, 511, 1056, SP);
        k_reduce<<<dim3(1024, NB), dim3(256), 0, stream>>>(
            pr, ee + NGRID + 1, NI2, NINT, NGRID, (long long)N2G, SP);

        // dots (Ae inline); step slots red[8*step ..]
        k_dotAe<<<dim3(128, NB), dim3(256), 0, stream>>>(
            rr, ee, coef, red + 8 * step);
        if (step == 0)
            k_update<<<dim3((NB * N2G + 255) / 256), dim3(256), 0, stream>>>(
                x0, ee, red);
    }
    k_fin<<<dim3(128, NB), dim3(256), 0, stream>>>(x0, ee, f, coef, red);
    k_final<<<dim3(1), dim3(1), 0, stream>>>(red, out);
}

// Round 9
// 660.399 us; speedup vs baseline: 1.0457x; 1.0457x over previous
//
#include <hip/hip_runtime.h>
#include <math.h>

#ifndef M_PI
#define M_PI 3.14159265358979323846
#endif

#define NGRID 513
#define NCELL 512
#define NINT  511
#define NB    4

constexpr int N2G = NGRID * NGRID;   // 263169
constexpr int NI2 = NINT * NINT;     // 261121
constexpr int NQ  = 257 * 257;       // 66049 (rh antisym quadrant)

// GEMM LDS row stride (ushorts). 40 measured-lowest conflicts (R7: 42 was
// WORSE, 4.05M vs 2.7M cycles; and timing insensitive to either -> LDS
// conflicts are off the critical path; keep 40).
#define LDSW 40

typedef unsigned short ushort;
typedef unsigned int uint32;
typedef __attribute__((ext_vector_type(8))) short short8;
typedef __attribute__((ext_vector_type(8))) unsigned short ushort8;
typedef __attribute__((ext_vector_type(4))) float f32x4;

// ---------------------------------------------------------------------------
// bf16 split helpers (RNE)
// ---------------------------------------------------------------------------
__device__ __forceinline__ ushort f2bf(float x) {
    unsigned u = __float_as_uint(x);
    unsigned r = u + 0x7FFFu + ((u >> 16) & 1u);
    return (ushort)(r >> 16);
}
__device__ __forceinline__ float bf2f(ushort h) {
    return __uint_as_float(((unsigned)h) << 16);
}

// rh antisymmetric-quadrant read: rq = batch base (257x257), (i,j) full-grid.
__device__ __forceinline__ float rhq_read(const float* __restrict__ rq,
                                          int i, int j) {
    float s = 1.0f;
    if (i > 256) { i = 512 - i; s = -s; }
    if (j > 256) { j = 512 - j; s = -s; }
    return s * rq[i * 257 + j];
}

// wt * ik2 complex scale (bitwise-identical to the original k_scale expression)
__device__ __forceinline__ float2 scale_wt(float x0, float x1, float wr, float wi,
                                           int gr, int gc) {
    int du = gr - 256, dv = gc - 256;
    float ik2;
    if (du == 0 && dv == 0)
        ik2 = 1.0f;
    else
        ik2 = (float)(1.0 / (9.869604401089358 * (double)(du * du + dv * dv)));
    return make_float2((x0 * wr - x1 * wi) * ik2, (x0 * wi + x1 * wr) * ik2);
}

// ---------------------------------------------------------------------------
// FEM Darcy operator at interior node (i,j), i,j in 1..511
// ---------------------------------------------------------------------------
__device__ __forceinline__ float darcyA(const float* __restrict__ x,
                                        const float* __restrict__ a,
                                        int i, int j) {
    const float c23 = 2.0f / 3.0f, c16 = 1.0f / 6.0f, c13 = 1.0f / 3.0f;
    float a00 = a[(i - 1) * NCELL + (j - 1)];
    float a01 = a[(i - 1) * NCELL + j];
    float a10 = a[i * NCELL + (j - 1)];
    float a11 = a[i * NCELL + j];
    const float* xm = x + (i - 1) * NGRID;
    const float* xc = x + i * NGRID;
    const float* xp = x + (i + 1) * NGRID;
    return c23 * (a00 + a01 + a10 + a11) * xc[j]
         - c16 * ((a00 + a01) * xm[j] + (a10 + a11) * xp[j]
                + (a00 + a10) * xc[j - 1] + (a01 + a11) * xc[j + 1])
         - c13 * (a00 * xm[j - 1] + a01 * xm[j + 1]
                + a10 * xp[j - 1] + a11 * xp[j + 1]);
}

// ---------------------------------------------------------------------------
// R20: 5 fused weighted-Jacobi sweeps per launch (validated).
// RES=1 additionally emits r = f - A x5 + transposed bf16 gemm1-B planes.
// ---------------------------------------------------------------------------
template <int RES>
__global__ __launch_bounds__(256) void k_jacobi5R(
    const float* __restrict__ xin, const float* __restrict__ a,
    const float* __restrict__ f, const float* __restrict__ dinv,
    float* __restrict__ out, float* __restrict__ rout,
    ushort* __restrict__ tBh, ushort* __restrict__ tBl) {
    constexpr int H  = RES ? 6 : 5;
    constexpr int SX = 16 + 2 * H;        // 28 / 26
    constexpr int SA = SX - 1;            // 27 / 25
    constexpr int SF = 16 + 2 * (H - 1);  // 26 / 24
    __shared__ float sx[SX][SX];
    __shared__ float sa[SA][SA + 1];
    __shared__ float sf[SF][SF];
    __shared__ float sd[SF][SF];
    __shared__ float sp[2][SF][SF + 2];
    __shared__ float st[16][17];
    const float c23 = 2.0f / 3.0f, c16 = 1.0f / 6.0f, c13 = 1.0f / 3.0f;
    int b = blockIdx.z;
    const float* xb = xin + (long long)b * N2G;
    const float* ab = a + (long long)b * NCELL * NCELL;
    const float* fb = f + (long long)b * N2G;
    const float* db = dinv + (long long)b * NI2;
    int ox = blockIdx.x * 16, oy = blockIdx.y * 16;
    int tx = threadIdx.x, ty = threadIdx.y;
    int tid = ty * 16 + tx;

    for (int idx = tid; idx < SX * SX; idx += 256) {
        int ly = idx / SX, lx = idx % SX;
        int gy = oy - H + ly, gx = ox - H + lx;
        bool in = (gy >= 0 && gy < NGRID && gx >= 0 && gx < NGRID);
        sx[ly][lx] = in ? xb[(long long)gy * NGRID + gx] : 0.0f;
    }
    for (int idx = tid; idx < SA * SA; idx += 256) {
        int ly = idx / SA, lx = idx % SA;
        int gy = oy - H + ly, gx = ox - H + lx;
        bool in = (gy >= 0 && gy < NCELL && gx >= 0 && gx < NCELL);
        sa[ly][lx] = in ? ab[(long long)gy * NCELL + gx] : 0.0f;
    }
    for (int idx = tid; idx < SF * SF; idx += 256) {
        int ly = idx / SF, lx = idx % SF;
        int gy = oy - (H - 1) + ly, gx = ox - (H - 1) + lx;
        bool ing = (gy >= 0 && gy < NGRID && gx >= 0 && gx < NGRID);
        bool itr = (gy >= 1 && gy <= NINT && gx >= 1 && gx <= NINT);
        sf[ly][lx] = ing ? fb[(long long)gy * NGRID + gx] : 0.0f;
        sd[ly][lx] = itr ? db[(long long)(gy - 1) * NINT + (gx - 1)] : 0.0f;
    }
    __syncthreads();

    for (int idx = tid; idx < SF * SF; idx += 256) {
        int ly = idx / SF, lx = idx % SF;
        int gy = oy - (H - 1) + ly, gx = ox - (H - 1) + lx;
        float v = 0.0f;
        if (gy >= 0 && gy < NGRID && gx >= 0 && gx < NGRID) {
            float xc = sx[ly + 1][lx + 1];
            if (gy >= 1 && gy <= NINT && gx >= 1 && gx <= NINT) {
                float a00 = sa[ly][lx], a01 = sa[ly][lx + 1];
                float a10 = sa[ly + 1][lx], a11 = sa[ly + 1][lx + 1];
                float Ax = c23 * (a00 + a01 + a10 + a11) * xc
                    - c16 * ((a00 + a01) * sx[ly][lx + 1] + (a10 + a11) * sx[ly + 2][lx + 1]
                           + (a00 + a10) * sx[ly + 1][lx] + (a01 + a11) * sx[ly + 1][lx + 2])
                    - c13 * (a00 * sx[ly][lx] + a01 * sx[ly][lx + 2]
                           + a10 * sx[ly + 2][lx] + a11 * sx[ly + 2][lx + 2]);
                v = xc + 0.75f * sd[ly][lx] * (sf[ly][lx] - Ax);
            } else {
                v = xc;
            }
        }
        sp[0][ly][lx] = v;
    }
    __syncthreads();

    #pragma unroll 1
    for (int s = 2; s <= 5; ++s) {
        int sz = 16 + 2 * (H - s);
        int cur = (s - 1) & 1, prv = s & 1;
        for (int idx = tid; idx < sz * sz; idx += 256) {
            int ly = idx / sz, lx = idx % sz;
            int gy = oy - (H - s) + ly, gx = ox - (H - s) + lx;
            float v = 0.0f;
            if (gy >= 0 && gy < NGRID && gx >= 0 && gx < NGRID) {
                float xc = sp[prv][ly + 1][lx + 1];
                if (gy >= 1 && gy <= NINT && gx >= 1 && gx <= NINT) {
                    int ar = ly + s - 1, ac = lx + s - 1;
                    float a00 = sa[ar][ac], a01 = sa[ar][ac + 1];
                    float a10 = sa[ar + 1][ac], a11 = sa[ar + 1][ac + 1];
                    float Ax = c23 * (a00 + a01 + a10 + a11) * xc
                        - c16 * ((a00 + a01) * sp[prv][ly][lx + 1] + (a10 + a11) * sp[prv][ly + 2][lx + 1]
                               + (a00 + a10) * sp[prv][ly + 1][lx] + (a01 + a11) * sp[prv][ly + 1][lx + 2])
                        - c13 * (a00 * sp[prv][ly][lx] + a01 * sp[prv][ly][lx + 2]
                               + a10 * sp[prv][ly + 2][lx] + a11 * sp[prv][ly + 2][lx + 2]);
                    int fr = ly + s - 1, fc = lx + s - 1;
                    v = xc + 0.75f * sd[fr][fc] * (sf[fr][fc] - Ax);
                } else {
                    v = xc;
                }
            }
            sp[cur][ly][lx] = v;
        }
        __syncthreads();
    }

    int gy = oy + ty, gx = ox + tx;
    long long gidx = (long long)b * N2G + (long long)gy * NGRID + gx;
    if constexpr (!RES) {
        if (gy < NGRID && gx < NGRID) out[gidx] = sp[0][ty][tx];
    } else {
        float rv = 0.0f;
        if (gy < NGRID && gx < NGRID) {
            float x5 = sp[0][ty + 1][tx + 1];
            out[gidx] = x5;
            if (gy >= 1 && gy <= NINT && gx >= 1 && gx <= NINT) {
                float a00 = sa[ty + 5][tx + 5], a01 = sa[ty + 5][tx + 6];
                float a10 = sa[ty + 6][tx + 5], a11 = sa[ty + 6][tx + 6];
                float Ax = c23 * (a00 + a01 + a10 + a11) * x5
                    - c16 * ((a00 + a01) * sp[0][ty][tx + 1] + (a10 + a11) * sp[0][ty + 2][tx + 1]
                           + (a00 + a10) * sp[0][ty + 1][tx] + (a01 + a11) * sp[0][ty + 1][tx + 2])
                    - c13 * (a00 * sp[0][ty][tx] + a01 * sp[0][ty][tx + 2]
                           + a10 * sp[0][ty + 2][tx] + a11 * sp[0][ty + 2][tx + 2]);
                rv = sf[ty + 5][tx + 5] - Ax;
            } else {
                rv = sf[ty + 5][tx + 5];
            }
            rout[gidx] = rv;
        }
        st[ty][tx] = rv;
        __syncthreads();
        int i2 = blockIdx.y * 16 + tx;   // = k+1
        int j2 = blockIdx.x * 16 + ty;   // = n+1
        if (i2 >= 1 && i2 <= NINT && j2 >= 1 && j2 <= NINT) {
            float r2 = st[tx][ty];
            ushort h = f2bf(r2);
            long long o = (long long)b * 511 * 512
                        + (long long)(j2 - 1) * 512 + (i2 - 1);
            tBh[o] = h;
            tBl[o] = f2bf(r2 - bf2f(h));
        }
    }
}

// ---------------------------------------------------------------------------
// R21: trig tables (3074 distinct double sin/cos values; expressions
// identical to the originals -> downstream bits unchanged).
// ---------------------------------------------------------------------------
__global__ void k_tables(double* __restrict__ tabD, double* __restrict__ tabC,
                         double* __restrict__ tabS) {
    int t = blockIdx.x * 256 + threadIdx.x;
    if (t < 1024) tabD[t] = sin((M_PI / 512.0) * (double)t);
    if (t < 1025) {
        double ang = (2.0 * M_PI / 1025.0) * (double)t;
        tabC[t] = cos(ang);
        tabS[t] = sin(ang);
    }
}

__device__ __forceinline__ void wsplit(double v, ushort* Dh, ushort* Dl,
                                       long long idx) {
    float vf = (float)v;
    ushort h = f2bf(vf);
    Dh[idx] = h;
    Dl[idx] = f2bf(vf - bf2f(h));
}

// R21: all static bf16 matrices + dinv in ONE kernel (region-partitioned).
constexpr long long R_DSTA = 513LL * 512;       // 262656
constexpr long long R_DSTB = 513LL * 512;       // 262656
constexpr long long R_FA   = 511LL * 1056;      // 539616
constexpr long long R_FB   = 1022LL * 1056;     // 1079232
constexpr long long R_DINV = (long long)NB * NI2; // 1044484
constexpr long long R_TOT  = R_DSTA + R_DSTB + R_FA + R_FB + R_DINV;

__global__ void k_genAll(const double* __restrict__ tabD,
                         const double* __restrict__ tabC,
                         const double* __restrict__ tabS,
                         const float* __restrict__ coef,
                         float* __restrict__ dinv,
                         ushort* __restrict__ GAh, ushort* __restrict__ GAl,
                         ushort* __restrict__ GBh, ushort* __restrict__ GBl,
                         ushort* __restrict__ FAh, ushort* __restrict__ FAl,
                         ushort* __restrict__ FBh, ushort* __restrict__ FBl) {
    long long gid = (long long)blockIdx.x * 256 + threadIdx.x;
    if (gid < R_DSTA) {  // DST A: sin(pi t/512)
        int idx = (int)gid;
        int u = idx / 512, k = idx % 512;
        double v = 0.0;
        if (k < 511) {
            int t = ((u - 256) * (k + 1)) % 1024;
            if (t < 0) t += 1024;
            v = tabD[t];
        }
        wsplit(v, GAh, GAl, idx);
        return;
    }
    gid -= R_DSTA;
    if (gid < R_DSTB) {  // DST B^T scaled
        int idx = (int)gid;
        int v2 = idx / 512, k = idx % 512;
        double val = 0.0;
        if (k < 511) {
            int t = ((v2 - 256) * (k + 1)) % 1024;
            if (t < 0) t += 1024;
            val = tabD[t] * (-1.0 / 262144.0);
        }
        wsplit(val, GBh, GBl, idx);
        return;
    }
    gid -= R_DSTB;
    if (gid < R_FA) {    // F A (511 x 1056)
        int idx = (int)gid;
        int y = idx / 1056, k = idx % 1056;
        double v = 0.0;
        if (k < 1026) {
            int m = (k < 513) ? k : (k - 513);
            long t = ((long)y * (m - 255)) % 1025;
            if (t < 0) t += 1025;
            v = (k < 513) ? tabC[t] : -tabS[t];
        }
        wsplit(v, FAh, FAl, idx);
        return;
    }
    gid -= R_FA;
    if (gid < R_FB) {    // F B (1022 x 1056)
        int idx = (int)gid;
        int n = idx / 1056, k = idx % 1056;
        double v = 0.0;
        if (k < 1026) {
            int m = (k < 513) ? k : (k - 513);
            int y = (n < 511) ? n : (n - 511);
            long t = ((long)y * (m - 255)) % 1025;
            if (t < 0) t += 1025;
            bool ktop = (k < 513), nleft = (n < 511);
            if (ktop && nleft)        v = tabC[t];
            else if (ktop && !nleft)  v = -tabS[t];
            else if (!ktop && nleft)  v = tabS[t];
            else                      v = tabC[t];
        }
        wsplit(v, FBh, FBl, idx);
        return;
    }
    gid -= R_FB;
    if (gid < R_DINV) {  // dinv
        long long idx = gid;
        int b = (int)(idx / NI2);
        int rem = (int)(idx % NI2);
        int p = rem / NINT, q = rem % NINT;
        const float* ab = coef + (long long)b * NCELL * NCELL;
        float s = ab[p * NCELL + q] + ab[p * NCELL + q + 1]
                + ab[(p + 1) * NCELL + q] + ab[(p + 1) * NCELL + q + 1];
        dinv[idx] = 1.0f / ((2.0f / 3.0f) * s);
    }
}

// ---------------------------------------------------------------------------
// Fused split-K reduce + bf16 convert (GEMM->GEMM handoffs).
// ---------------------------------------------------------------------------
__global__ void k_redA(const float* __restrict__ P, int nsplit, int Mr,
                       ushort* __restrict__ Dh, ushort* __restrict__ Dl) {
    int b = blockIdx.y;
    int idx = blockIdx.x * 256 + threadIdx.x;
    if (idx >= Mr * 512) return;
    int m = idx / 512, k = idx % 512;
    float v = 0.0f;
    if (k < 511) {
        long long base = (long long)m * 511 + k;
        long long str = (long long)Mr * 511;
        #pragma unroll 4
        for (int s = 0; s < nsplit; ++s)
            v += P[((long long)b * nsplit + s) * str + base];
    }
    long long o = (long long)b * Mr * 512 + idx;
    ushort h = f2bf(v);
    Dh[o] = h;
    Dl[o] = f2bf(v - bf2f(h));
}

__global__ void k_redBt(const float* __restrict__ P, int nsplit,
                        ushort* __restrict__ Dh, ushort* __restrict__ Dl) {
    int b = blockIdx.y;
    int idx = blockIdx.x * 256 + threadIdx.x;
    if (idx >= 511 * 1056) return;
    int n = idx / 1056, k = idx % 1056;
    float v = 0.0f;
    if (k < 1026) {
        int row = (k < 513) ? n : (511 + n);
        int col = (k < 513) ? k : (k - 513);
        long long base = (long long)row * 513 + col;
        float acc = 0.0f;
        #pragma unroll 4
        for (int s = 0; s < nsplit; ++s)
            acc += P[((long long)b * nsplit + s) * (1022LL * 513) + base];
        v = (k < 513) ? acc : -acc;
    }
    long long o = (long long)b * 511 * 1056 + idx;
    ushort h = f2bf(v);
    Dh[o] = h;
    Dl[o] = f2bf(v - bf2f(h));
}

// ---------------------------------------------------------------------------
// MFMA real GEMM, 3-term split-bf16 (hh + hl + lh), 16x16x32 bf16 MFMA.
// R24: register-prefetch software pipeline (resubmitted R25 after infra
// failure). Latency-bound kernel (MfmaUtil 12.5%, VALUBusy 10%, occ 17%,
// HBM 35%): next tile's global loads issue BEFORE current tile's
// fragment-reads + 48 MFMAs, hiding HBM/L2 latency under compute.
// Same arithmetic, same order, same LDS layout (LDSW=40).
// ---------------------------------------------------------------------------
__global__ __launch_bounds__(256) void k_mgemm(
    const ushort* __restrict__ Ah, const ushort* __restrict__ Al, long long bsA,
    const ushort* __restrict__ Bh, const ushort* __restrict__ Bl, long long bsB,
    float* __restrict__ C, long long bsC,
    int M, int N, int Kp, int nsplit) {
    __shared__ ushort sAh[128 * LDSW];
    __shared__ ushort sAl[128 * LDSW];
    __shared__ ushort sBh[128 * LDSW];
    __shared__ ushort sBl[128 * LDSW];

    int bz = blockIdx.z, b = bz / nsplit, ks = bz % nsplit;
    int kchunk = (((Kp + nsplit - 1) / nsplit) + 31) & ~31;
    int kbeg = ks * kchunk;
    int kend = min(Kp, kbeg + kchunk);

    Ah += b * bsA; Al += b * bsA;
    Bh += b * bsB; Bl += b * bsB;
    C += ((long long)b * nsplit + ks) * bsC;

    int bm = blockIdx.y * 128, bn = blockIdx.x * 128;
    int tid = threadIdx.x;
    int wave = tid >> 6, lane = tid & 63;
    int wm = (wave >> 1) * 64, wn = (wave & 1) * 64;
    int quad = lane >> 4, l16 = lane & 15;

    f32x4 zf = {0.f, 0.f, 0.f, 0.f};
    f32x4 acc[4][4];
    #pragma unroll
    for (int i = 0; i < 4; ++i)
        #pragma unroll
        for (int j = 0; j < 4; ++j) acc[i][j] = zf;

    int srow = tid >> 2;
    int sk8 = (tid & 3) * 8;
    bool inA0 = (bm + srow) < M,       inB0 = (bn + srow) < N;
    bool inA1 = (bm + srow + 64) < M,  inB1 = (bn + srow + 64) < N;
    const ushort* gA0h = Ah + (long long)(bm + srow) * Kp + sk8;
    const ushort* gA0l = Al + (long long)(bm + srow) * Kp + sk8;
    const ushort* gA1h = gA0h + 64LL * Kp;
    const ushort* gA1l = gA0l + 64LL * Kp;
    const ushort* gB0h = Bh + (long long)(bn + srow) * Kp + sk8;
    const ushort* gB0l = Bl + (long long)(bn + srow) * Kp + sk8;
    const ushort* gB1h = gB0h + 64LL * Kp;
    const ushort* gB1l = gB0l + 64LL * Kp;

    ushort8 z8 = {0, 0, 0, 0, 0, 0, 0, 0};
    ushort8 pAh0, pAl0, pAh1, pAl1, pBh0, pBl0, pBh1, pBl1;

    auto load_tile = [&](int kt) {
        pAh0 = inA0 ? *(const ushort8*)(gA0h + kt) : z8;
        pAl0 = inA0 ? *(const ushort8*)(gA0l + kt) : z8;
        pAh1 = inA1 ? *(const ushort8*)(gA1h + kt) : z8;
        pAl1 = inA1 ? *(const ushort8*)(gA1l + kt) : z8;
        pBh0 = inB0 ? *(const ushort8*)(gB0h + kt) : z8;
        pBl0 = inB0 ? *(const ushort8*)(gB0l + kt) : z8;
        pBh1 = inB1 ? *(const ushort8*)(gB1h + kt) : z8;
        pBl1 = inB1 ? *(const ushort8*)(gB1l + kt) : z8;
    };
    auto store_tile = [&]() {
        *(ushort8*)(sAh + srow * LDSW + sk8) = pAh0;
        *(ushort8*)(sAl + srow * LDSW + sk8) = pAl0;
        *(ushort8*)(sAh + (srow + 64) * LDSW + sk8) = pAh1;
        *(ushort8*)(sAl + (srow + 64) * LDSW + sk8) = pAl1;
        *(ushort8*)(sBh + srow * LDSW + sk8) = pBh0;
        *(ushort8*)(sBl + srow * LDSW + sk8) = pBl0;
        *(ushort8*)(sBh + (srow + 64) * LDSW + sk8) = pBh1;
        *(ushort8*)(sBl + (srow + 64) * LDSW + sk8) = pBl1;
    };

    // prologue: stage first tile
    load_tile(kbeg);
    store_tile();
    __syncthreads();

    for (int kt = kbeg; kt < kend; kt += 32) {
        bool more = (kt + 32) < kend;   // block-uniform
        if (more) load_tile(kt + 32);   // issue next-tile loads EARLY

        short8 afh[4], afl[4], bfh[4], bfl[4];
        #pragma unroll
        for (int t = 0; t < 4; ++t) {
            int ar = wm + t * 16 + l16;
            afh[t] = *(const short8*)(sAh + ar * LDSW + quad * 8);
            afl[t] = *(const short8*)(sAl + ar * LDSW + quad * 8);
            int br = wn + t * 16 + l16;
            bfh[t] = *(const short8*)(sBh + br * LDSW + quad * 8);
            bfl[t] = *(const short8*)(sBl + br * LDSW + quad * 8);
        }
        #pragma unroll
        for (int mt = 0; mt < 4; ++mt)
            #pragma unroll
            for (int nt = 0; nt < 4; ++nt) {
                acc[mt][nt] = __builtin_amdgcn_mfma_f32_16x16x32_bf16(
                    afh[mt], bfh[nt], acc[mt][nt], 0, 0, 0);
                acc[mt][nt] = __builtin_amdgcn_mfma_f32_16x16x32_bf16(
                    afh[mt], bfl[nt], acc[mt][nt], 0, 0, 0);
                acc[mt][nt] = __builtin_amdgcn_mfma_f32_16x16x32_bf16(
                    afl[mt], bfh[nt], acc[mt][nt], 0, 0, 0);
            }
        __syncthreads();                // everyone done READING current LDS
        if (more) store_tile();         // overwrite with prefetched tile
        __syncthreads();                // LDS ready for next iter
    }

    #pragma unroll
    for (int mt = 0; mt < 4; ++mt) {
        #pragma unroll
        for (int r = 0; r < 4; ++r) {
            int gm = bm + wm + mt * 16 + quad * 4 + r;
            if (gm >= M) continue;
            long long rowoff = (long long)gm * N;
            #pragma unroll
            for (int nt = 0; nt < 4; ++nt) {
                int gn = bn + wn + nt * 16 + l16;
                if (gn < N) C[rowoff + gn] = acc[mt][nt][r];
            }
        }
    }
}

// ---------------------------------------------------------------------------
// Sum nsplit dense [M x N] partials -> strided fp32 output (row stride ldo).
// ---------------------------------------------------------------------------
__global__ void k_reduce(const float* __restrict__ Pr,
                         float* __restrict__ outR,
                         int MN, int N, int ldo, long long bsOut, int nsplit) {
    int b = blockIdx.y;
    for (int idx = blockIdx.x * 256 + threadIdx.x; idx < MN;
         idx += gridDim.x * 256) {
        float sr = 0.0f;
        #pragma unroll 4
        for (int s = 0; s < nsplit; ++s)
            sr += Pr[((long long)b * nsplit + s) * MN + idx];
        int m = idx / N, n = idx - m * N;
        outR[(long long)b * bsOut + (long long)m * ldo + n] = sr;
    }
}

// ---------------------------------------------------------------------------
// Composed conv-chain (validated R17): each 3-conv chain == one complex 7x7.
// ---------------------------------------------------------------------------
__device__ __forceinline__ float2 cmul(float2 a, float2 b) {
    return make_float2(a.x * b.x - a.y * b.y, a.x * b.y + a.y * b.x);
}

__global__ void k_compose(const float* __restrict__ w1r, const float* __restrict__ w1i,
                          const float* __restrict__ w2r, const float* __restrict__ w2i,
                          const float* __restrict__ w3r, const float* __restrict__ w3i,
                          float* __restrict__ kc) {
    int chain = blockIdx.x, b = blockIdx.y;
    int tid = threadIdx.x;  // 128
    __shared__ float2 sW1[4][9], sW2[16][9], sW3[4][9], sW21[4][25];
    for (int idx = tid; idx < 36; idx += 128) {
        int c = idx / 9, s = idx % 9, p = s / 3, q = s % 3;
        if (chain == 0) {
            int i1 = b * 36 + c * 9 + p * 3 + q;
            sW1[c][s] = make_float2(w1r[i1], w1i[i1]);
            sW3[c][s] = make_float2(w3r[i1], w3i[i1]);
        } else {
            int it = b * 36 + c * 9 + q * 3 + p;
            sW1[c][s] = make_float2(w3r[it], -w3i[it]);
            sW3[c][s] = make_float2(w1r[it], -w1i[it]);
        }
    }
    for (int idx = tid; idx < 144; idx += 128) {
        int co = idx / 36, r = idx % 36, ci = r / 9, s = r % 9, p = s / 3, q = s % 3;
        int iw = (chain == 0) ? (b * 144 + co * 36 + ci * 9 + p * 3 + q)
                              : (b * 144 + ci * 36 + co * 9 + q * 3 + p);
        float iv = w2i[iw];
        sW2[co * 4 + ci][s] = make_float2(w2r[iw], (chain == 0) ? iv : -iv);
    }
    __syncthreads();
    for (int idx = tid; idx < 100; idx += 128) {
        int cm = idx / 25, r = idx % 25, di = r / 5 - 2, dj = r % 5 - 2;
        float2 acc = make_float2(0.f, 0.f);
        for (int c1 = 0; c1 < 4; ++c1)
            for (int p = 0; p < 3; ++p)
                for (int q = 0; q < 3; ++q) {
                    int ei = di - (p - 1) + 1, ej = dj - (q - 1) + 1;
                    if (ei >= 0 && ei < 3 && ej >= 0 && ej < 3) {
                        float2 t = cmul(sW2[cm * 4 + c1][p * 3 + q], sW1[c1][ei * 3 + ej]);
                        acc.x += t.x; acc.y += t.y;
                    }
                }
        sW21[cm][r] = acc;
    }
    __syncthreads();
    for (int idx = tid; idx < 49; idx += 128) {
        int di = idx / 7 - 3, dj = idx % 7 - 3;
        float2 acc = make_float2(0.f, 0.f);
        for (int cm = 0; cm < 4; ++cm)
            for (int p = 0; p < 3; ++p)
                for (int q = 0; q < 3; ++q) {
                    int ei = di - (p - 1), ej = dj - (q - 1);
                    if (ei >= -2 && ei <= 2 && ej >= -2 && ej <= 2) {
                        float2 t = cmul(sW3[cm][p * 3 + q], sW21[cm][(ei + 2) * 5 + (ej + 2)]);
                        acc.x += t.x; acc.y += t.y;
                    }
                }
        ((float2*)kc)[(b * 2 + chain) * 49 + idx] = acc;
    }
}

// main composed 7x7 conv (R19 re-tile: 16x32 output tile, 2 rows/thread).
template <int MODE>
__global__ __launch_bounds__(256) void k_conv7(
    const float* __restrict__ xr, const float* __restrict__ xi,
    const float* __restrict__ wtr, const float* __restrict__ wti,
    const float* __restrict__ kc,
    float* __restrict__ outr, float* __restrict__ outi,
    ushort* __restrict__ oAh, ushort* __restrict__ oAl) {
    constexpr bool CPLX = (MODE == 1);
    __shared__ float2 tile[38][23];
    __shared__ float2 kt[49];
    int b = blockIdx.z;
    int tid = threadIdx.y * 16 + threadIdx.x;
    const float2* kb = (const float2*)kc + (b * 2 + MODE) * 49;
    for (int idx = tid; idx < 49; idx += 256) kt[idx] = kb[idx];
    int row_base = blockIdx.y * 32 - 3;
    int col_base = blockIdx.x * 16 - 3;
    const float* rq = xr + (long long)b * NQ;
    for (int idx = tid; idx < 38 * 22; idx += 256) {
        int r = idx / 22, c = idx % 22;
        int gr = row_base + r, gc = col_base + c;
        float vr = 0.0f, vi = 0.0f;
        if (gr >= 0 && gr < NGRID && gc >= 0 && gc < NGRID) {
            if (MODE == 0) {
                vr = rhq_read(rq, gr, gc);
            } else {
                long long g = (long long)b * N2G + (long long)gr * NGRID + gc;
                float2 sc = scale_wt(xr[g], xi[g], wtr[g], wti[g], gr, gc);
                vr = sc.x; vi = sc.y;
            }
        }
        tile[r][c] = make_float2(vr, vi);
    }
    __syncthreads();

    int tx = threadIdx.x, r0 = threadIdx.y * 2;
    float2 acc[2];
    acc[0] = make_float2(0.f, 0.f);
    acc[1] = make_float2(0.f, 0.f);
    #pragma unroll
    for (int t = 0; t < 7; ++t) {
        float2 kv[7];
        #pragma unroll
        for (int s = 0; s < 7; ++s) kv[s] = kt[s * 7 + t];
        #pragma unroll
        for (int rr = 0; rr < 8; ++rr) {
            float2 xv = tile[r0 + rr][tx + t];
            #pragma unroll
            for (int s = 0; s < 7; ++s) {
                int orow = rr - s;
                if (orow >= 0 && orow < 2) {
                    acc[orow].x += kv[s].x * xv.x;
                    acc[orow].y += kv[s].y * xv.x;
                    if (CPLX) {
                        acc[orow].x -= kv[s].y * xv.y;
                        acc[orow].y += kv[s].x * xv.y;
                    }
                }
            }
        }
    }
    int gc = blockIdx.x * 16 + tx;
    if (gc >= NGRID) return;
    #pragma unroll
    for (int r = 0; r < 2; ++r) {
        int gr = blockIdx.y * 32 + r0 + r;
        if (gr < NGRID) {
            if (MODE == 0) {
                long long g = (long long)b * N2G + (long long)gr * NGRID + gc;
                outr[g] = acc[r].x;
                outi[g] = acc[r].y;
            } else {
                long long o = (long long)b * 513 * 1056
                            + (long long)gr * 1056 + gc;
                ushort h = f2bf(acc[r].x);
                oAh[o] = h;
                oAl[o] = f2bf(acc[r].x - bf2f(h));
                ushort h2 = f2bf(acc[r].y);
                oAh[o + 513] = h2;
                oAl[o + 513] = f2bf(acc[r].y - bf2f(h2));
            }
        }
    }
}

// exact sequential recompute of the width-2 border ring (validated R4).
template <int CHAIN>
__global__ __launch_bounds__(256) void k_ring7(
    const float* __restrict__ xr, const float* __restrict__ xi,
    const float* __restrict__ wtr, const float* __restrict__ wti,
    const float* __restrict__ w1r, const float* __restrict__ w1i,
    const float* __restrict__ w2r, const float* __restrict__ w2i,
    const float* __restrict__ w3r, const float* __restrict__ w3i,
    float* __restrict__ outr, float* __restrict__ outi,
    ushort* __restrict__ oAh, ushort* __restrict__ oAl) {
    constexpr bool CPLX = (CHAIN == 1);
    __shared__ float2 W1s[4][9], W2s[16][9], W3s[4][9];
    __shared__ float2 Y[4][4][68];
    __shared__ float2 Z[4][3][66];
    int side = blockIdx.y, b = blockIdx.z;
    int u0 = blockIdx.x * 64;
    int ulo = (side < 2) ? 0 : 2;
    int uhi = (side < 2) ? (NGRID - 1) : (NGRID - 3);
    if (u0 > uhi) return;
    int tid = threadIdx.x;
    const float* rq = xr + (long long)b * NQ;

    for (int idx = tid; idx < 36; idx += 256) {
        int c = idx / 9, s = idx % 9, p = s / 3, q = s % 3;
        if (CHAIN == 0) {
            int i1 = b * 36 + c * 9 + p * 3 + q;
            W1s[c][s] = make_float2(w1r[i1], w1i[i1]);
            W3s[c][s] = make_float2(w3r[i1], w3i[i1]);
        } else {
            int it = b * 36 + c * 9 + q * 3 + p;
            W1s[c][s] = make_float2(w3r[it], -w3i[it]);
            W3s[c][s] = make_float2(w1r[it], -w1i[it]);
        }
    }
    for (int idx = tid; idx < 144; idx += 256) {
        int co = idx / 36, r = idx % 36, ci = r / 9, s = r % 9, p = s / 3, q = s % 3;
        int iw = (CHAIN == 0) ? (b * 144 + co * 36 + ci * 9 + p * 3 + q)
                              : (b * 144 + ci * 36 + co * 9 + q * 3 + p);
        float iv = w2i[iw];
        W2s[co * 4 + ci][s] = make_float2(w2r[iw], (CHAIN == 0) ? iv : -iv);
    }
    __syncthreads();

    for (int idx = tid; idx < 4 * 4 * 68; idx += 256) {
        int ch = idx / (4 * 68), r = idx % (4 * 68), d = r / 68, uu = r % 68;
        int u = u0 - 2 + uu;
        float2 acc = make_float2(0.f, 0.f);
        if (u >= 0 && u < NGRID) {
            int i, j;
            if (side == 0)      { i = d;       j = u; }
            else if (side == 1) { i = 512 - d; j = u; }
            else if (side == 2) { i = u;       j = d; }
            else                { i = u;       j = 512 - d; }
            for (int p = 0; p < 3; ++p)
                for (int q = 0; q < 3; ++q) {
                    int ii = i + p - 1, jj = j + q - 1;
                    if (ii >= 0 && ii < NGRID && jj >= 0 && jj < NGRID) {
                        float vr, vi;
                        if (CHAIN == 0) {
                            vr = rhq_read(rq, ii, jj);
                            vi = 0.0f;
                        } else {
                            long long g = (long long)b * N2G
                                        + (long long)ii * NGRID + jj;
                            float2 sc = scale_wt(xr[g], xi[g], wtr[g], wti[g],
                                                 ii, jj);
                            vr = sc.x; vi = sc.y;
                        }
                        float2 w = W1s[ch][p * 3 + q];
                        acc.x += w.x * vr - w.y * vi;
                        acc.y += w.x * vi + w.y * vr;
                    }
                }
        }
        Y[ch][d][uu] = acc;
    }
    __syncthreads();

    for (int idx = tid; idx < 4 * 3 * 66; idx += 256) {
        int co = idx / (3 * 66), r = idx % (3 * 66), d = r / 66, uu = r % 66;
        int u = u0 - 1 + uu;
        float2 acc = make_float2(0.f, 0.f);
        if (u >= 0 && u < NGRID) {
            for (int p = 0; p < 3; ++p)
                for (int q = 0; q < 3; ++q) {
                    int dd, du;
                    if (side == 0)      { dd = p - 1; du = q - 1; }
                    else if (side == 1) { dd = 1 - p; du = q - 1; }
                    else if (side == 2) { dd = q - 1; du = p - 1; }
                    else                { dd = 1 - q; du = p - 1; }
                    int d2 = d + dd, uy = uu + 1 + du;
                    if (d2 >= 0) {
                        for (int ci = 0; ci < 4; ++ci) {
                            float2 yv = Y[ci][d2][uy];
                            float2 w = W2s[co * 4 + ci][p * 3 + q];
                            acc.x += w.x * yv.x - w.y * yv.y;
                            acc.y += w.x * yv.y + w.y * yv.x;
                        }
                    }
                }
        }
        Z[co][d][uu] = acc;
    }
    __syncthreads();

    for (int idx = tid; idx < 128; idx += 256) {
        int d = idx / 64, uu = idx % 64;
        int u = u0 + uu;
        if (u < ulo || u > uhi) continue;
        float2 acc = make_float2(0.f, 0.f);
        for (int p = 0; p < 3; ++p)
            for (int q = 0; q < 3; ++q) {
                int dd, du;
                if (side == 0)      { dd = p - 1; du = q - 1; }
                else if (side == 1) { dd = 1 - p; du = q - 1; }
                else if (side == 2) { dd = q - 1; du = p - 1; }
                else                { dd = 1 - q; du = p - 1; }
                int d2 = d + dd, uz = uu + 1 + du;
                if (d2 >= 0) {
                    for (int ci = 0; ci < 4; ++ci) {
                        float2 zv = Z[ci][d2][uz];
                        float2 w = W3s[ci][p * 3 + q];
                        acc.x += w.x * zv.x - w.y * zv.y;
                        acc.y += w.x * zv.y + w.y * zv.x;
                    }
                }
            }
        int i, j;
        if (side == 0)      { i = d;       j = u; }
        else if (side == 1) { i = 512 - d; j = u; }
        else if (side == 2) { i = u;       j = d; }
        else                { i = u;       j = 512 - d; }
        if (CHAIN == 0) {
            long long g = (long long)b * N2G + (long long)i * NGRID + j;
            outr[g] = acc.x;
            outi[g] = acc.y;
        } else {
            long long o = (long long)b * 513 * 1056 + (long long)i * 1056 + j;
            ushort h = f2bf(acc.x);
            oAh[o] = h;
            oAl[o] = f2bf(acc.x - bf2f(h));
            ushort h2 = f2bf(acc.y);
            oAh[o + 513] = h2;
            oAl[o + 513] = f2bf(acc.y - bf2f(h2));
        }
    }
}

// ---------------------------------------------------------------------------
// red[2b] += sum(r*e), red[2b+1] += sum((A e)*e), Ae computed inline.
// ---------------------------------------------------------------------------
__global__ void k_dotAe(const float* __restrict__ r, const float* __restrict__ e,
                        const float* __restrict__ a, float* __restrict__ red) {
    int b = blockIdx.y;
    const float* rb = r + (long long)b * N2G;
    const float* eb = e + (long long)b * N2G;
    const float* ab = a + (long long)b * NCELL * NCELL;
    float s1 = 0.0f, s2 = 0.0f;
    for (int idx = blockIdx.x * blockDim.x + threadIdx.x; idx < NI2;
         idx += gridDim.x * blockDim.x) {
        int i = idx / NINT + 1, j = idx % NINT + 1;
        long long g = (long long)i * NGRID + j;
        float ev = eb[g];
        float Ax = darcyA(eb, ab, i, j);
        s1 += rb[g] * ev;
        s2 += Ax * ev;
    }
    #pragma unroll
    for (int o = 32; o > 0; o >>= 1) {
        s1 += __shfl_down(s1, o);
        s2 += __shfl_down(s2, o);
    }
    __shared__ float l1[4], l2[4];
    int wid = threadIdx.x >> 6;
    if ((threadIdx.x & 63) == 0) { l1[wid] = s1; l2[wid] = s2; }
    __syncthreads();
    if (threadIdx.x == 0) {
        atomicAdd(&red[2 * b], l1[0] + l1[1] + l1[2] + l1[3]);
        atomicAdd(&red[2 * b + 1], l2[0] + l2[1] + l2[2] + l2[3]);
    }
}

__global__ void k_update(float* __restrict__ x, const float* __restrict__ e,
                         const float* __restrict__ red) {
    long long idx = (long long)blockIdx.x * blockDim.x + threadIdx.x;
    if (idx >= (long long)NB * N2G) return;
    int b = (int)(idx / N2G);
    float alpha = red[2 * b] / red[2 * b + 1];
    x[idx] += alpha * e[idx];
}

// ---------------------------------------------------------------------------
// final: r = f - A(x + alpha e) fused with norm accumulation.
// ---------------------------------------------------------------------------
__global__ void k_fin(const float* __restrict__ x, const float* __restrict__ e,
                      const float* __restrict__ f, const float* __restrict__ a,
                      float* __restrict__ red) {
    const float c23 = 2.0f / 3.0f, c16 = 1.0f / 6.0f, c13 = 1.0f / 3.0f;
    int b = blockIdx.y;
    long long base = (long long)b * N2G;
    const float* ab = a + (long long)b * NCELL * NCELL;
    float alpha = red[8 + 2 * b] / red[8 + 2 * b + 1];
    float s1 = 0.0f, s2 = 0.0f;
    for (int idx = blockIdx.x * blockDim.x + threadIdx.x; idx < N2G;
         idx += gridDim.x * blockDim.x) {
        int i = idx / NGRID, j = idx - i * NGRID;
        float fv = f[base + idx];
        float rv = fv;
        if (i >= 1 && i <= NINT && j >= 1 && j <= NINT) {
            float a00 = ab[(i - 1) * NCELL + (j - 1)];
            float a01 = ab[(i - 1) * NCELL + j];
            float a10 = ab[i * NCELL + (j - 1)];
            float a11 = ab[i * NCELL + j];
            long long gm = base + (long long)(i - 1) * NGRID + j;
            long long gc = base + (long long)i * NGRID + j;
            long long gp = base + (long long)(i + 1) * NGRID + j;
            float xmm = x[gm - 1] + alpha * e[gm - 1];
            float xm0 = x[gm] + alpha * e[gm];
            float xmp = x[gm + 1] + alpha * e[gm + 1];
            float xcm = x[gc - 1] + alpha * e[gc - 1];
            float xc0 = x[gc] + alpha * e[gc];
            float xcp = x[gc + 1] + alpha * e[gc + 1];
            float xpm = x[gp - 1] + alpha * e[gp - 1];
            float xp0 = x[gp] + alpha * e[gp];
            float xpp = x[gp + 1] + alpha * e[gp + 1];
            float Ax = c23 * (a00 + a01 + a10 + a11) * xc0
                - c16 * ((a00 + a01) * xm0 + (a10 + a11) * xp0
                       + (a00 + a10) * xcm + (a01 + a11) * xcp)
                - c13 * (a00 * xmm + a01 * xmp + a10 * xpm + a11 * xpp);
            rv = fv - Ax;
        }
        s1 += rv * rv;
        s2 += fv * fv;
    }
    #pragma unroll
    for (int o = 32; o > 0; o >>= 1) {
        s1 += __shfl_down(s1, o);
        s2 += __shfl_down(s2, o);
    }
    __shared__ float l1[4], l2[4];
    int wid = threadIdx.x >> 6;
    if ((threadIdx.x & 63) == 0) { l1[wid] = s1; l2[wid] = s2; }
    __syncthreads();
    if (threadIdx.x == 0) {
        atomicAdd(&red[16], l1[0] + l1[1] + l1[2] + l1[3]);
        atomicAdd(&red[17], l2[0] + l2[1] + l2[2] + l2[3]);
    }
}

__global__ void k_final(const float* __restrict__ red, float* __restrict__ out) {
    out[0] = sqrtf(red[16] / red[17]);
}

// ---------------------------------------------------------------------------
extern "C" void kernel_launch(void* const* d_in, const int* in_sizes, int n_in,
                              void* d_out, int out_size, void* d_ws, size_t ws_size,
                              hipStream_t stream) {
    (void)in_sizes; (void)n_in; (void)out_size; (void)ws_size;
    const float* f    = (const float*)d_in[0];
    const float* coef = (const float*)d_in[1];
    const float* w1r  = (const float*)d_in[3];
    const float* w1i  = (const float*)d_in[4];
    const float* w2r  = (const float*)d_in[5];
    const float* w2i  = (const float*)d_in[6];
    const float* w3r  = (const float*)d_in[7];
    const float* w3i  = (const float*)d_in[8];
    const float* wtr  = (const float*)d_in[9];
    const float* wti  = (const float*)d_in[10];
    float* out = (float*)d_out;

    float* ws = (float*)d_ws;
    size_t off = 0;
    auto alloc = [&](long long n) {
        float* p = ws + off;
        off += (size_t)((n + 3) & ~3LL);
        return p;
    };
    float* x0   = alloc((long long)NB * N2G);
    float* x1   = alloc((long long)NB * N2G);
    float* rr   = alloc((long long)NB * N2G);
    float* ee   = alloc((long long)NB * N2G);
    float* dinv = alloc((long long)NB * NI2);
    float* c1r  = alloc((long long)NB * 4 * N2G);
    float* c1i  = alloc((long long)NB * 4 * N2G);
    float* c2r  = alloc((long long)NB * 4 * N2G);
    float* c2i  = alloc((long long)NB * 4 * N2G);
    float* pr   = c1r;  // partial span (c1r..c2i contiguous, ~67 MB)
    float* or_  = alloc((long long)NB * N2G);
    float* oi_  = alloc((long long)NB * N2G);
    float* rhq  = alloc((long long)NB * NQ);   // rh antisym quadrant 257x257
    float* red  = alloc(20);
    ushort* sGh  = (ushort*)alloc(513 * 512 / 2);
    ushort* sGl  = (ushort*)alloc(513 * 512 / 2);
    ushort* sGth = (ushort*)alloc(513 * 512 / 2);
    ushort* sGtl = (ushort*)alloc(513 * 512 / 2);
    ushort* sFAh = (ushort*)alloc(511 * 1056 / 2);
    ushort* sFAl = (ushort*)alloc(511 * 1056 / 2);
    ushort* sFBh = (ushort*)alloc(1022 * 1056 / 2);
    ushort* sFBl = (ushort*)alloc(1022 * 1056 / 2);
    ushort* dA2h = (ushort*)alloc((long long)NB * 257 * 512 / 2);  // gemm2 A
    ushort* dA2l = (ushort*)alloc((long long)NB * 257 * 512 / 2);
    ushort* dA3h = (ushort*)alloc((long long)NB * 513 * 1056 / 2); // gemm3 B
    ushort* dA3l = (ushort*)alloc((long long)NB * 513 * 1056 / 2);
    ushort* dB1h = (ushort*)alloc((long long)NB * 511 * 512 / 2);  // gemm1 B
    ushort* dB1l = (ushort*)alloc((long long)NB * 511 * 512 / 2);
    ushort* dB4h = (ushort*)alloc((long long)NB * 511 * 1056 / 2); // gemm4 B
    ushort* dB4l = (ushort*)alloc((long long)NB * 511 * 1056 / 2);
    float* kcomp = alloc(NB * 2 * 49 * 2);   // composed 7x7 chain kernels
    double* tabD = (double*)alloc(1024 * 2); // sin(pi t/512), t<1024
    double* tabC = (double*)alloc(1026 * 2); // cos(2pi t/1025), t<1025
    double* tabS = (double*)alloc(1026 * 2); // sin(2pi t/1025), t<1025

    dim3 blk2(16, 16);
    dim3 grdS(33, 33, NB);
    dim3 grdC(33, 17, NB);   // conv7: 16x32 output tile per block (R19)
    dim3 grdR(9, 4, NB);     // ring7: 64-wide segments x 4 sides
    const int SP = 4;

    hipMemsetAsync(x0, 0, (size_t)NB * N2G * sizeof(float), stream);
    hipMemsetAsync(ee, 0, (size_t)NB * N2G * sizeof(float), stream);
    hipMemsetAsync(red, 0, 20 * sizeof(float), stream);
    hipMemsetAsync(dA3h, 0, (size_t)NB * 513 * 1056 * 2 * 2, stream);
    hipMemsetAsync(dB1h, 0, (size_t)NB * 511 * 512 * 2 * 2, stream);
    k_tables<<<dim3(5), dim3(256), 0, stream>>>(tabD, tabC, tabS);
    k_genAll<<<dim3((unsigned)((R_TOT + 255) / 256)), dim3(256), 0, stream>>>(
        tabD, tabC, tabS, coef, dinv,
        sGh, sGl, sGth, sGtl, sFAh, sFAl, sFBh, sFBl);
    k_compose<<<dim3(2, NB), dim3(128), 0, stream>>>(w1r, w1i, w2r, w2i, w3r, w3i, kcomp);

    for (int step = 0; step < 2; ++step) {
        // 10 weighted-Jacobi sweeps: x0 -> x1 (5), x1 -> x0 (5 + residual +
        // bf16 transpose planes for gemm1 B)
        k_jacobi5R<0><<<grdS, blk2, 0, stream>>>(
            x0, coef, f, dinv, x1, nullptr, nullptr, nullptr);
        k_jacobi5R<1><<<grdS, blk2, 0, stream>>>(
            x1, coef, f, dinv, x0, rr, dB1h, dB1l);

        // ---- H_apply ----
        // gemm1: t2 = G(257x511) * rI(511x511)   [antisym: M 513 -> 257]
        k_mgemm<<<dim3(4, 3, NB * SP), dim3(256), 0, stream>>>(
            sGh, sGl, 0, dB1h, dB1l, (long long)511 * 512,
            pr, (long long)257 * 511, 257, 511, 512, SP);
        k_redA<<<dim3((257 * 512 + 255) / 256, NB), dim3(256), 0, stream>>>(
            pr, SP, 257, dA2h, dA2l);
        // gemm2: rh_q = t2(257x511) * Gt(511x257) [antisym: N 513 -> 257]
        k_mgemm<<<dim3(3, 3, NB * SP), dim3(256), 0, stream>>>(
            dA2h, dA2l, (long long)257 * 512, sGth, sGtl, 0,
            pr, (long long)NQ, 257, 257, 512, SP);
        k_reduce<<<dim3(259, NB), dim3(256), 0, stream>>>(
            pr, rhq, NQ, 257, 257, (long long)NQ, SP);

        // forward conv chain (rh mirror-read) -> or_/oi_
        k_conv7<0><<<grdC, blk2, 0, stream>>>(
            rhq, nullptr, nullptr, nullptr, kcomp, or_, oi_, nullptr, nullptr);
        k_ring7<0><<<grdR, dim3(256), 0, stream>>>(
            rhq, nullptr, nullptr, nullptr,
            w1r, w1i, w2r, w2i, w3r, w3i, or_, oi_, nullptr, nullptr);
        // adjoint conv chain (fused wt*ik2 scale on load) -> bf16 dA3 planes
        k_conv7<1><<<grdC, blk2, 0, stream>>>(
            or_, oi_, wtr, wti, kcomp, nullptr, nullptr, dA3h, dA3l);
        k_ring7<1><<<grdR, dim3(256), 0, stream>>>(
            or_, oi_, wtr, wti,
            w1r, w1i, w2r, w2i, w3r, w3i, nullptr, nullptr, dA3h, dA3l);

        // gemm3' (transposed): P'[n<1022][m<513] = sFB * dA3^T
        k_mgemm<<<dim3(5, 8, NB * 4), dim3(256), 0, stream>>>(
            sFBh, sFBl, 0, dA3h, dA3l, (long long)513 * 1056,
            pr, 1022LL * 513, 1022, 513, 1056, 4);
        k_redBt<<<dim3(2109, NB), dim3(256), 0, stream>>>(pr, 4, dB4h, dB4l);
        // gemm4: e = [Fr|Fi](511x1026) * [t2r;-t2i](1026x511)
        k_mgemm<<<dim3(4, 4, NB * SP), dim3(256), 0, stream>>>(
            sFAh, sFAl, 0, dB4h, dB4l, (long long)511 * 1056,
            pr, (long long)NI2, 511, 511, 1056, SP);
        k_reduce<<<dim3(1024, NB), dim3(256), 0, stream>>>(
            pr, ee + NGRID + 1, NI2, NINT, NGRID, (long long)N2G, SP);

        // dots (Ae inline); step slots red[8*step ..]
        k_dotAe<<<dim3(128, NB), dim3(256), 0, stream>>>(
            rr, ee, coef, red + 8 * step);
        if (step == 0)
            k_update<<<dim3((NB * N2G + 255) / 256), dim3(256), 0, stream>>>(
                x0, ee, red);
    }
    k_fin<<<dim3(128, NB), dim3(256), 0, stream>>>(x0, ee, f, coef, red);
    k_final<<<dim3(1), dim3(1), 0, stream>>>(red, out);
}

// Round 10
// 649.984 us; speedup vs baseline: 1.0625x; 1.0160x over previous
//
#include <hip/hip_runtime.h>
#include <math.h>

#ifndef M_PI
#define M_PI 3.14159265358979323846
#endif

#define NGRID 513
#define NCELL 512
#define NINT  511
#define NB    4

constexpr int N2G = NGRID * NGRID;   // 263169
constexpr int NI2 = NINT * NINT;     // 261121
constexpr int NQ  = 257 * 257;       // 66049 (rh antisym quadrant)

#define LDSW 40

typedef unsigned short ushort;
typedef unsigned int uint32;
typedef __attribute__((ext_vector_type(8))) short short8;
typedef __attribute__((ext_vector_type(8))) unsigned short ushort8;
typedef __attribute__((ext_vector_type(4))) float f32x4;

// ---------------------------------------------------------------------------
// bf16 split helpers (RNE)
// ---------------------------------------------------------------------------
__device__ __forceinline__ ushort f2bf(float x) {
    unsigned u = __float_as_uint(x);
    unsigned r = u + 0x7FFFu + ((u >> 16) & 1u);
    return (ushort)(r >> 16);
}
__device__ __forceinline__ float bf2f(ushort h) {
    return __uint_as_float(((unsigned)h) << 16);
}

// rh antisymmetric-quadrant read: rq = batch base (257x257), (i,j) full-grid.
__device__ __forceinline__ float rhq_read(const float* __restrict__ rq,
                                          int i, int j) {
    float s = 1.0f;
    if (i > 256) { i = 512 - i; s = -s; }
    if (j > 256) { j = 512 - j; s = -s; }
    return s * rq[i * 257 + j];
}

// wt * ik2 complex scale (bitwise-identical to the original k_scale expression)
__device__ __forceinline__ float2 scale_wt(float x0, float x1, float wr, float wi,
                                           int gr, int gc) {
    int du = gr - 256, dv = gc - 256;
    float ik2;
    if (du == 0 && dv == 0)
        ik2 = 1.0f;
    else
        ik2 = (float)(1.0 / (9.869604401089358 * (double)(du * du + dv * dv)));
    return make_float2((x0 * wr - x1 * wi) * ik2, (x0 * wi + x1 * wr) * ik2);
}

// ---------------------------------------------------------------------------
// FEM Darcy operator at interior node (i,j), i,j in 1..511
// ---------------------------------------------------------------------------
__device__ __forceinline__ float darcyA(const float* __restrict__ x,
                                        const float* __restrict__ a,
                                        int i, int j) {
    const float c23 = 2.0f / 3.0f, c16 = 1.0f / 6.0f, c13 = 1.0f / 3.0f;
    float a00 = a[(i - 1) * NCELL + (j - 1)];
    float a01 = a[(i - 1) * NCELL + j];
    float a10 = a[i * NCELL + (j - 1)];
    float a11 = a[i * NCELL + j];
    const float* xm = x + (i - 1) * NGRID;
    const float* xc = x + i * NGRID;
    const float* xp = x + (i + 1) * NGRID;
    return c23 * (a00 + a01 + a10 + a11) * xc[j]
         - c16 * ((a00 + a01) * xm[j] + (a10 + a11) * xp[j]
                + (a00 + a10) * xc[j - 1] + (a01 + a11) * xc[j + 1])
         - c13 * (a00 * xm[j - 1] + a01 * xm[j + 1]
                + a10 * xp[j - 1] + a11 * xp[j + 1]);
}

// ---------------------------------------------------------------------------
// R20: 5 fused weighted-Jacobi sweeps per launch (validated).
// RES=1 additionally emits r = f - A x5 + transposed bf16 gemm1-B planes.
// ---------------------------------------------------------------------------
template <int RES>
__global__ __launch_bounds__(256) void k_jacobi5R(
    const float* __restrict__ xin, const float* __restrict__ a,
    const float* __restrict__ f, const float* __restrict__ dinv,
    float* __restrict__ out, float* __restrict__ rout,
    ushort* __restrict__ tBh, ushort* __restrict__ tBl) {
    constexpr int H  = RES ? 6 : 5;
    constexpr int SX = 16 + 2 * H;        // 28 / 26
    constexpr int SA = SX - 1;            // 27 / 25
    constexpr int SF = 16 + 2 * (H - 1);  // 26 / 24
    __shared__ float sx[SX][SX];
    __shared__ float sa[SA][SA + 1];
    __shared__ float sf[SF][SF];
    __shared__ float sd[SF][SF];
    __shared__ float sp[2][SF][SF + 2];
    __shared__ float st[16][17];
    const float c23 = 2.0f / 3.0f, c16 = 1.0f / 6.0f, c13 = 1.0f / 3.0f;
    int b = blockIdx.z;
    const float* xb = xin + (long long)b * N2G;
    const float* ab = a + (long long)b * NCELL * NCELL;
    const float* fb = f + (long long)b * N2G;
    const float* db = dinv + (long long)b * NI2;
    int ox = blockIdx.x * 16, oy = blockIdx.y * 16;
    int tx = threadIdx.x, ty = threadIdx.y;
    int tid = ty * 16 + tx;

    for (int idx = tid; idx < SX * SX; idx += 256) {
        int ly = idx / SX, lx = idx % SX;
        int gy = oy - H + ly, gx = ox - H + lx;
        bool in = (gy >= 0 && gy < NGRID && gx >= 0 && gx < NGRID);
        sx[ly][lx] = in ? xb[(long long)gy * NGRID + gx] : 0.0f;
    }
    for (int idx = tid; idx < SA * SA; idx += 256) {
        int ly = idx / SA, lx = idx % SA;
        int gy = oy - H + ly, gx = ox - H + lx;
        bool in = (gy >= 0 && gy < NCELL && gx >= 0 && gx < NCELL);
        sa[ly][lx] = in ? ab[(long long)gy * NCELL + gx] : 0.0f;
    }
    for (int idx = tid; idx < SF * SF; idx += 256) {
        int ly = idx / SF, lx = idx % SF;
        int gy = oy - (H - 1) + ly, gx = ox - (H - 1) + lx;
        bool ing = (gy >= 0 && gy < NGRID && gx >= 0 && gx < NGRID);
        bool itr = (gy >= 1 && gy <= NINT && gx >= 1 && gx <= NINT);
        sf[ly][lx] = ing ? fb[(long long)gy * NGRID + gx] : 0.0f;
        sd[ly][lx] = itr ? db[(long long)(gy - 1) * NINT + (gx - 1)] : 0.0f;
    }
    __syncthreads();

    for (int idx = tid; idx < SF * SF; idx += 256) {
        int ly = idx / SF, lx = idx % SF;
        int gy = oy - (H - 1) + ly, gx = ox - (H - 1) + lx;
        float v = 0.0f;
        if (gy >= 0 && gy < NGRID && gx >= 0 && gx < NGRID) {
            float xc = sx[ly + 1][lx + 1];
            if (gy >= 1 && gy <= NINT && gx >= 1 && gx <= NINT) {
                float a00 = sa[ly][lx], a01 = sa[ly][lx + 1];
                float a10 = sa[ly + 1][lx], a11 = sa[ly + 1][lx + 1];
                float Ax = c23 * (a00 + a01 + a10 + a11) * xc
                    - c16 * ((a00 + a01) * sx[ly][lx + 1] + (a10 + a11) * sx[ly + 2][lx + 1]
                           + (a00 + a10) * sx[ly + 1][lx] + (a01 + a11) * sx[ly + 1][lx + 2])
                    - c13 * (a00 * sx[ly][lx] + a01 * sx[ly][lx + 2]
                           + a10 * sx[ly + 2][lx] + a11 * sx[ly + 2][lx + 2]);
                v = xc + 0.75f * sd[ly][lx] * (sf[ly][lx] - Ax);
            } else {
                v = xc;
            }
        }
        sp[0][ly][lx] = v;
    }
    __syncthreads();

    #pragma unroll 1
    for (int s = 2; s <= 5; ++s) {
        int sz = 16 + 2 * (H - s);
        int cur = (s - 1) & 1, prv = s & 1;
        for (int idx = tid; idx < sz * sz; idx += 256) {
            int ly = idx / sz, lx = idx % sz;
            int gy = oy - (H - s) + ly, gx = ox - (H - s) + lx;
            float v = 0.0f;
            if (gy >= 0 && gy < NGRID && gx >= 0 && gx < NGRID) {
                float xc = sp[prv][ly + 1][lx + 1];
                if (gy >= 1 && gy <= NINT && gx >= 1 && gx <= NINT) {
                    int ar = ly + s - 1, ac = lx + s - 1;
                    float a00 = sa[ar][ac], a01 = sa[ar][ac + 1];
                    float a10 = sa[ar + 1][ac], a11 = sa[ar + 1][ac + 1];
                    float Ax = c23 * (a00 + a01 + a10 + a11) * xc
                        - c16 * ((a00 + a01) * sp[prv][ly][lx + 1] + (a10 + a11) * sp[prv][ly + 2][lx + 1]
                               + (a00 + a10) * sp[prv][ly + 1][lx] + (a01 + a11) * sp[prv][ly + 1][lx + 2])
                        - c13 * (a00 * sp[prv][ly][lx] + a01 * sp[prv][ly][lx + 2]
                               + a10 * sp[prv][ly + 2][lx] + a11 * sp[prv][ly + 2][lx + 2]);
                    int fr = ly + s - 1, fc = lx + s - 1;
                    v = xc + 0.75f * sd[fr][fc] * (sf[fr][fc] - Ax);
                } else {
                    v = xc;
                }
            }
            sp[cur][ly][lx] = v;
        }
        __syncthreads();
    }

    int gy = oy + ty, gx = ox + tx;
    long long gidx = (long long)b * N2G + (long long)gy * NGRID + gx;
    if constexpr (!RES) {
        if (gy < NGRID && gx < NGRID) out[gidx] = sp[0][ty][tx];
    } else {
        float rv = 0.0f;
        if (gy < NGRID && gx < NGRID) {
            float x5 = sp[0][ty + 1][tx + 1];
            out[gidx] = x5;
            if (gy >= 1 && gy <= NINT && gx >= 1 && gx <= NINT) {
                float a00 = sa[ty + 5][tx + 5], a01 = sa[ty + 5][tx + 6];
                float a10 = sa[ty + 6][tx + 5], a11 = sa[ty + 6][tx + 6];
                float Ax = c23 * (a00 + a01 + a10 + a11) * x5
                    - c16 * ((a00 + a01) * sp[0][ty][tx + 1] + (a10 + a11) * sp[0][ty + 2][tx + 1]
                           + (a00 + a10) * sp[0][ty + 1][tx] + (a01 + a11) * sp[0][ty + 1][tx + 2])
                    - c13 * (a00 * sp[0][ty][tx] + a01 * sp[0][ty][tx + 2]
                           + a10 * sp[0][ty + 2][tx] + a11 * sp[0][ty + 2][tx + 2]);
                rv = sf[ty + 5][tx + 5] - Ax;
            } else {
                rv = sf[ty + 5][tx + 5];
            }
            rout[gidx] = rv;
        }
        st[ty][tx] = rv;
        __syncthreads();
        int i2 = blockIdx.y * 16 + tx;   // = k+1
        int j2 = blockIdx.x * 16 + ty;   // = n+1
        if (i2 >= 1 && i2 <= NINT && j2 >= 1 && j2 <= NINT) {
            float r2 = st[tx][ty];
            ushort h = f2bf(r2);
            long long o = (long long)b * 511 * 512
                        + (long long)(j2 - 1) * 512 + (i2 - 1);
            tBh[o] = h;
            tBl[o] = f2bf(r2 - bf2f(h));
        }
    }
}

// ---------------------------------------------------------------------------
// R21: trig tables (3074 distinct double sin/cos values; expressions
// identical to the originals -> downstream bits unchanged).
// ---------------------------------------------------------------------------
__global__ void k_tables(double* __restrict__ tabD, double* __restrict__ tabC,
                         double* __restrict__ tabS) {
    int t = blockIdx.x * 256 + threadIdx.x;
    if (t < 1024) tabD[t] = sin((M_PI / 512.0) * (double)t);
    if (t < 1025) {
        double ang = (2.0 * M_PI / 1025.0) * (double)t;
        tabC[t] = cos(ang);
        tabS[t] = sin(ang);
    }
}

__device__ __forceinline__ void wsplit(double v, ushort* Dh, ushort* Dl,
                                       long long idx) {
    float vf = (float)v;
    ushort h = f2bf(vf);
    Dh[idx] = h;
    Dl[idx] = f2bf(vf - bf2f(h));
}

// R21: all static bf16 matrices + dinv in ONE kernel (region-partitioned).
constexpr long long R_DSTA = 513LL * 512;       // 262656
constexpr long long R_DSTB = 513LL * 512;       // 262656
constexpr long long R_FA   = 511LL * 1056;      // 539616
constexpr long long R_FB   = 1022LL * 1056;     // 1079232
constexpr long long R_DINV = (long long)NB * NI2; // 1044484
constexpr long long R_TOT  = R_DSTA + R_DSTB + R_FA + R_FB + R_DINV;

__global__ void k_genAll(const double* __restrict__ tabD,
                         const double* __restrict__ tabC,
                         const double* __restrict__ tabS,
                         const float* __restrict__ coef,
                         float* __restrict__ dinv,
                         ushort* __restrict__ GAh, ushort* __restrict__ GAl,
                         ushort* __restrict__ GBh, ushort* __restrict__ GBl,
                         ushort* __restrict__ FAh, ushort* __restrict__ FAl,
                         ushort* __restrict__ FBh, ushort* __restrict__ FBl) {
    long long gid = (long long)blockIdx.x * 256 + threadIdx.x;
    if (gid < R_DSTA) {  // DST A: sin(pi t/512)
        int idx = (int)gid;
        int u = idx / 512, k = idx % 512;
        double v = 0.0;
        if (k < 511) {
            int t = ((u - 256) * (k + 1)) % 1024;
            if (t < 0) t += 1024;
            v = tabD[t];
        }
        wsplit(v, GAh, GAl, idx);
        return;
    }
    gid -= R_DSTA;
    if (gid < R_DSTB) {  // DST B^T scaled
        int idx = (int)gid;
        int v2 = idx / 512, k = idx % 512;
        double val = 0.0;
        if (k < 511) {
            int t = ((v2 - 256) * (k + 1)) % 1024;
            if (t < 0) t += 1024;
            val = tabD[t] * (-1.0 / 262144.0);
        }
        wsplit(val, GBh, GBl, idx);
        return;
    }
    gid -= R_DSTB;
    if (gid < R_FA) {    // F A (511 x 1056)
        int idx = (int)gid;
        int y = idx / 1056, k = idx % 1056;
        double v = 0.0;
        if (k < 1026) {
            int m = (k < 513) ? k : (k - 513);
            long t = ((long)y * (m - 255)) % 1025;
            if (t < 0) t += 1025;
            v = (k < 513) ? tabC[t] : -tabS[t];
        }
        wsplit(v, FAh, FAl, idx);
        return;
    }
    gid -= R_FA;
    if (gid < R_FB) {    // F B (1022 x 1056)
        int idx = (int)gid;
        int n = idx / 1056, k = idx % 1056;
        double v = 0.0;
        if (k < 1026) {
            int m = (k < 513) ? k : (k - 513);
            int y = (n < 511) ? n : (n - 511);
            long t = ((long)y * (m - 255)) % 1025;
            if (t < 0) t += 1025;
            bool ktop = (k < 513), nleft = (n < 511);
            if (ktop && nleft)        v = tabC[t];
            else if (ktop && !nleft)  v = -tabS[t];
            else if (!ktop && nleft)  v = tabS[t];
            else                      v = tabC[t];
        }
        wsplit(v, FBh, FBl, idx);
        return;
    }
    gid -= R_FB;
    if (gid < R_DINV) {  // dinv
        long long idx = gid;
        int b = (int)(idx / NI2);
        int rem = (int)(idx % NI2);
        int p = rem / NINT, q = rem % NINT;
        const float* ab = coef + (long long)b * NCELL * NCELL;
        float s = ab[p * NCELL + q] + ab[p * NCELL + q + 1]
                + ab[(p + 1) * NCELL + q] + ab[(p + 1) * NCELL + q + 1];
        dinv[idx] = 1.0f / ((2.0f / 3.0f) * s);
    }
}

// ---------------------------------------------------------------------------
// Fused split-K reduce + bf16 convert (GEMM->GEMM handoffs).
// ---------------------------------------------------------------------------
__global__ void k_redA(const float* __restrict__ P, int nsplit, int Mr,
                       ushort* __restrict__ Dh, ushort* __restrict__ Dl) {
    int b = blockIdx.y;
    int idx = blockIdx.x * 256 + threadIdx.x;
    if (idx >= Mr * 512) return;
    int m = idx / 512, k = idx % 512;
    float v = 0.0f;
    if (k < 511) {
        long long base = (long long)m * 511 + k;
        long long str = (long long)Mr * 511;
        #pragma unroll 4
        for (int s = 0; s < nsplit; ++s)
            v += P[((long long)b * nsplit + s) * str + base];
    }
    long long o = (long long)b * Mr * 512 + idx;
    ushort h = f2bf(v);
    Dh[o] = h;
    Dl[o] = f2bf(v - bf2f(h));
}

__global__ void k_redBt(const float* __restrict__ P, int nsplit,
                        ushort* __restrict__ Dh, ushort* __restrict__ Dl) {
    int b = blockIdx.y;
    int idx = blockIdx.x * 256 + threadIdx.x;
    if (idx >= 511 * 1056) return;
    int n = idx / 1056, k = idx % 1056;
    float v = 0.0f;
    if (k < 1026) {
        int row = (k < 513) ? n : (511 + n);
        int col = (k < 513) ? k : (k - 513);
        long long base = (long long)row * 513 + col;
        float acc = 0.0f;
        #pragma unroll 4
        for (int s = 0; s < nsplit; ++s)
            acc += P[((long long)b * nsplit + s) * (1022LL * 513) + base];
        v = (k < 513) ? acc : -acc;
    }
    long long o = (long long)b * 511 * 1056 + idx;
    ushort h = f2bf(v);
    Dh[o] = h;
    Dl[o] = f2bf(v - bf2f(h));
}

// ---------------------------------------------------------------------------
// MFMA real GEMM, 3-term split-bf16 (hh + hl + lh), 16x16x32 bf16 MFMA.
// R26: XCD-aware block swizzle (guide T1). R9 counters: FETCH 73MB vs
// ~22MB unique operands = 3.4x HBM over-fetch because panel-sharing blocks
// round-robin across the 8 per-XCD L2s. Bijective remap (total blocks
// divisible by 8 for ALL four GEMM launches: 192/144/640/256) gives each
// XCD a contiguous chunk -> whole (batch,split) slices (~1.9MB) fit its
// 4MB L2. Pure index remap; output bitwise identical.
// ---------------------------------------------------------------------------
__global__ __launch_bounds__(256) void k_mgemm(
    const ushort* __restrict__ Ah, const ushort* __restrict__ Al, long long bsA,
    const ushort* __restrict__ Bh, const ushort* __restrict__ Bl, long long bsB,
    float* __restrict__ C, long long bsC,
    int M, int N, int Kp, int nsplit) {
    __shared__ ushort sAh[128 * LDSW];
    __shared__ ushort sAl[128 * LDSW];
    __shared__ ushort sBh[128 * LDSW];
    __shared__ ushort sBl[128 * LDSW];

    // T1 swizzle: physical XCD (fid%8) gets contiguous work-chunk
    int gxd = gridDim.x, gyd = gridDim.y;
    int total = gxd * gyd * gridDim.z;
    int fid = blockIdx.x + gxd * (blockIdx.y + gyd * blockIdx.z);
    int cpx = total >> 3;                   // total % 8 == 0 at all call sites
    int swz = (fid & 7) * cpx + (fid >> 3);
    int bxi = swz % gxd;
    int tmp2 = swz / gxd;
    int byi = tmp2 % gyd;
    int bzi = tmp2 / gyd;

    int bz = bzi, b = bz / nsplit, ks = bz % nsplit;
    int kchunk = (((Kp + nsplit - 1) / nsplit) + 31) & ~31;
    int kbeg = ks * kchunk;
    int kend = min(Kp, kbeg + kchunk);

    Ah += b * bsA; Al += b * bsA;
    Bh += b * bsB; Bl += b * bsB;
    C += ((long long)b * nsplit + ks) * bsC;

    int bm = byi * 128, bn = bxi * 128;
    int tid = threadIdx.x;
    int wave = tid >> 6, lane = tid & 63;
    int wm = (wave >> 1) * 64, wn = (wave & 1) * 64;
    int quad = lane >> 4, l16 = lane & 15;

    f32x4 zf = {0.f, 0.f, 0.f, 0.f};
    f32x4 acc[4][4];
    #pragma unroll
    for (int i = 0; i < 4; ++i)
        #pragma unroll
        for (int j = 0; j < 4; ++j) acc[i][j] = zf;

    int srow = tid >> 2;
    int sk8 = (tid & 3) * 8;
    bool inA0 = (bm + srow) < M,       inB0 = (bn + srow) < N;
    bool inA1 = (bm + srow + 64) < M,  inB1 = (bn + srow + 64) < N;
    const ushort* gA0h = Ah + (long long)(bm + srow) * Kp + sk8;
    const ushort* gA0l = Al + (long long)(bm + srow) * Kp + sk8;
    const ushort* gA1h = gA0h + 64LL * Kp;
    const ushort* gA1l = gA0l + 64LL * Kp;
    const ushort* gB0h = Bh + (long long)(bn + srow) * Kp + sk8;
    const ushort* gB0l = Bl + (long long)(bn + srow) * Kp + sk8;
    const ushort* gB1h = gB0h + 64LL * Kp;
    const ushort* gB1l = gB0l + 64LL * Kp;

    ushort8 z8 = {0, 0, 0, 0, 0, 0, 0, 0};
    ushort8 pAh0, pAl0, pAh1, pAl1, pBh0, pBl0, pBh1, pBl1;

    auto load_tile = [&](int kt) {
        pAh0 = inA0 ? *(const ushort8*)(gA0h + kt) : z8;
        pAl0 = inA0 ? *(const ushort8*)(gA0l + kt) : z8;
        pAh1 = inA1 ? *(const ushort8*)(gA1h + kt) : z8;
        pAl1 = inA1 ? *(const ushort8*)(gA1l + kt) : z8;
        pBh0 = inB0 ? *(const ushort8*)(gB0h + kt) : z8;
        pBl0 = inB0 ? *(const ushort8*)(gB0l + kt) : z8;
        pBh1 = inB1 ? *(const ushort8*)(gB1h + kt) : z8;
        pBl1 = inB1 ? *(const ushort8*)(gB1l + kt) : z8;
    };
    auto store_tile = [&]() {
        *(ushort8*)(sAh + srow * LDSW + sk8) = pAh0;
        *(ushort8*)(sAl + srow * LDSW + sk8) = pAl0;
        *(ushort8*)(sAh + (srow + 64) * LDSW + sk8) = pAh1;
        *(ushort8*)(sAl + (srow + 64) * LDSW + sk8) = pAl1;
        *(ushort8*)(sBh + srow * LDSW + sk8) = pBh0;
        *(ushort8*)(sBl + srow * LDSW + sk8) = pBl0;
        *(ushort8*)(sBh + (srow + 64) * LDSW + sk8) = pBh1;
        *(ushort8*)(sBl + (srow + 64) * LDSW + sk8) = pBl1;
    };

    // prologue: stage first tile
    load_tile(kbeg);
    store_tile();
    __syncthreads();

    for (int kt = kbeg; kt < kend; kt += 32) {
        bool more = (kt + 32) < kend;   // block-uniform
        if (more) load_tile(kt + 32);   // issue next-tile loads EARLY

        short8 afh[4], afl[4], bfh[4], bfl[4];
        #pragma unroll
        for (int t = 0; t < 4; ++t) {
            int ar = wm + t * 16 + l16;
            afh[t] = *(const short8*)(sAh + ar * LDSW + quad * 8);
            afl[t] = *(const short8*)(sAl + ar * LDSW + quad * 8);
            int br = wn + t * 16 + l16;
            bfh[t] = *(const short8*)(sBh + br * LDSW + quad * 8);
            bfl[t] = *(const short8*)(sBl + br * LDSW + quad * 8);
        }
        #pragma unroll
        for (int mt = 0; mt < 4; ++mt)
            #pragma unroll
            for (int nt = 0; nt < 4; ++nt) {
                acc[mt][nt] = __builtin_amdgcn_mfma_f32_16x16x32_bf16(
                    afh[mt], bfh[nt], acc[mt][nt], 0, 0, 0);
                acc[mt][nt] = __builtin_amdgcn_mfma_f32_16x16x32_bf16(
                    afh[mt], bfl[nt], acc[mt][nt], 0, 0, 0);
                acc[mt][nt] = __builtin_amdgcn_mfma_f32_16x16x32_bf16(
                    afl[mt], bfh[nt], acc[mt][nt], 0, 0, 0);
            }
        __syncthreads();                // everyone done READING current LDS
        if (more) store_tile();         // overwrite with prefetched tile
        __syncthreads();                // LDS ready for next iter
    }

    #pragma unroll
    for (int mt = 0; mt < 4; ++mt) {
        #pragma unroll
        for (int r = 0; r < 4; ++r) {
            int gm = bm + wm + mt * 16 + quad * 4 + r;
            if (gm >= M) continue;
            long long rowoff = (long long)gm * N;
            #pragma unroll
            for (int nt = 0; nt < 4; ++nt) {
                int gn = bn + wn + nt * 16 + l16;
                if (gn < N) C[rowoff + gn] = acc[mt][nt][r];
            }
        }
    }
}

// ---------------------------------------------------------------------------
// Sum nsplit dense [M x N] partials -> strided fp32 output (row stride ldo).
// ---------------------------------------------------------------------------
__global__ void k_reduce(const float* __restrict__ Pr,
                         float* __restrict__ outR,
                         int MN, int N, int ldo, long long bsOut, int nsplit) {
    int b = blockIdx.y;
    for (int idx = blockIdx.x * 256 + threadIdx.x; idx < MN;
         idx += gridDim.x * 256) {
        float sr = 0.0f;
        #pragma unroll 4
        for (int s = 0; s < nsplit; ++s)
            sr += Pr[((long long)b * nsplit + s) * MN + idx];
        int m = idx / N, n = idx - m * N;
        outR[(long long)b * bsOut + (long long)m * ldo + n] = sr;
    }
}

// ---------------------------------------------------------------------------
// Composed conv-chain (validated R17): each 3-conv chain == one complex 7x7.
// ---------------------------------------------------------------------------
__device__ __forceinline__ float2 cmul(float2 a, float2 b) {
    return make_float2(a.x * b.x - a.y * b.y, a.x * b.y + a.y * b.x);
}

__global__ void k_compose(const float* __restrict__ w1r, const float* __restrict__ w1i,
                          const float* __restrict__ w2r, const float* __restrict__ w2i,
                          const float* __restrict__ w3r, const float* __restrict__ w3i,
                          float* __restrict__ kc) {
    int chain = blockIdx.x, b = blockIdx.y;
    int tid = threadIdx.x;  // 128
    __shared__ float2 sW1[4][9], sW2[16][9], sW3[4][9], sW21[4][25];
    for (int idx = tid; idx < 36; idx += 128) {
        int c = idx / 9, s = idx % 9, p = s / 3, q = s % 3;
        if (chain == 0) {
            int i1 = b * 36 + c * 9 + p * 3 + q;
            sW1[c][s] = make_float2(w1r[i1], w1i[i1]);
            sW3[c][s] = make_float2(w3r[i1], w3i[i1]);
        } else {
            int it = b * 36 + c * 9 + q * 3 + p;
            sW1[c][s] = make_float2(w3r[it], -w3i[it]);
            sW3[c][s] = make_float2(w1r[it], -w1i[it]);
        }
    }
    for (int idx = tid; idx < 144; idx += 128) {
        int co = idx / 36, r = idx % 36, ci = r / 9, s = r % 9, p = s / 3, q = s % 3;
        int iw = (chain == 0) ? (b * 144 + co * 36 + ci * 9 + p * 3 + q)
                              : (b * 144 + ci * 36 + co * 9 + q * 3 + p);
        float iv = w2i[iw];
        sW2[co * 4 + ci][s] = make_float2(w2r[iw], (chain == 0) ? iv : -iv);
    }
    __syncthreads();
    for (int idx = tid; idx < 100; idx += 128) {
        int cm = idx / 25, r = idx % 25, di = r / 5 - 2, dj = r % 5 - 2;
        float2 acc = make_float2(0.f, 0.f);
        for (int c1 = 0; c1 < 4; ++c1)
            for (int p = 0; p < 3; ++p)
                for (int q = 0; q < 3; ++q) {
                    int ei = di - (p - 1) + 1, ej = dj - (q - 1) + 1;
                    if (ei >= 0 && ei < 3 && ej >= 0 && ej < 3) {
                        float2 t = cmul(sW2[cm * 4 + c1][p * 3 + q], sW1[c1][ei * 3 + ej]);
                        acc.x += t.x; acc.y += t.y;
                    }
                }
        sW21[cm][r] = acc;
    }
    __syncthreads();
    for (int idx = tid; idx < 49; idx += 128) {
        int di = idx / 7 - 3, dj = idx % 7 - 3;
        float2 acc = make_float2(0.f, 0.f);
        for (int cm = 0; cm < 4; ++cm)
            for (int p = 0; p < 3; ++p)
                for (int q = 0; q < 3; ++q) {
                    int ei = di - (p - 1), ej = dj - (q - 1);
                    if (ei >= -2 && ei <= 2 && ej >= -2 && ej <= 2) {
                        float2 t = cmul(sW3[cm][p * 3 + q], sW21[cm][(ei + 2) * 5 + (ej + 2)]);
                        acc.x += t.x; acc.y += t.y;
                    }
                }
        ((float2*)kc)[(b * 2 + chain) * 49 + idx] = acc;
    }
}

// main composed 7x7 conv (R19 re-tile: 16x32 output tile, 2 rows/thread).
template <int MODE>
__global__ __launch_bounds__(256) void k_conv7(
    const float* __restrict__ xr, const float* __restrict__ xi,
    const float* __restrict__ wtr, const float* __restrict__ wti,
    const float* __restrict__ kc,
    float* __restrict__ outr, float* __restrict__ outi,
    ushort* __restrict__ oAh, ushort* __restrict__ oAl) {
    constexpr bool CPLX = (MODE == 1);
    __shared__ float2 tile[38][23];
    __shared__ float2 kt[49];
    int b = blockIdx.z;
    int tid = threadIdx.y * 16 + threadIdx.x;
    const float2* kb = (const float2*)kc + (b * 2 + MODE) * 49;
    for (int idx = tid; idx < 49; idx += 256) kt[idx] = kb[idx];
    int row_base = blockIdx.y * 32 - 3;
    int col_base = blockIdx.x * 16 - 3;
    const float* rq = xr + (long long)b * NQ;
    for (int idx = tid; idx < 38 * 22; idx += 256) {
        int r = idx / 22, c = idx % 22;
        int gr = row_base + r, gc = col_base + c;
        float vr = 0.0f, vi = 0.0f;
        if (gr >= 0 && gr < NGRID && gc >= 0 && gc < NGRID) {
            if (MODE == 0) {
                vr = rhq_read(rq, gr, gc);
            } else {
                long long g = (long long)b * N2G + (long long)gr * NGRID + gc;
                float2 sc = scale_wt(xr[g], xi[g], wtr[g], wti[g], gr, gc);
                vr = sc.x; vi = sc.y;
            }
        }
        tile[r][c] = make_float2(vr, vi);
    }
    __syncthreads();

    int tx = threadIdx.x, r0 = threadIdx.y * 2;
    float2 acc[2];
    acc[0] = make_float2(0.f, 0.f);
    acc[1] = make_float2(0.f, 0.f);
    #pragma unroll
    for (int t = 0; t < 7; ++t) {
        float2 kv[7];
        #pragma unroll
        for (int s = 0; s < 7; ++s) kv[s] = kt[s * 7 + t];
        #pragma unroll
        for (int rr = 0; rr < 8; ++rr) {
            float2 xv = tile[r0 + rr][tx + t];
            #pragma unroll
            for (int s = 0; s < 7; ++s) {
                int orow = rr - s;
                if (orow >= 0 && orow < 2) {
                    acc[orow].x += kv[s].x * xv.x;
                    acc[orow].y += kv[s].y * xv.x;
                    if (CPLX) {
                        acc[orow].x -= kv[s].y * xv.y;
                        acc[orow].y += kv[s].x * xv.y;
                    }
                }
            }
        }
    }
    int gc = blockIdx.x * 16 + tx;
    if (gc >= NGRID) return;
    #pragma unroll
    for (int r = 0; r < 2; ++r) {
        int gr = blockIdx.y * 32 + r0 + r;
        if (gr < NGRID) {
            if (MODE == 0) {
                long long g = (long long)b * N2G + (long long)gr * NGRID + gc;
                outr[g] = acc[r].x;
                outi[g] = acc[r].y;
            } else {
                long long o = (long long)b * 513 * 1056
                            + (long long)gr * 1056 + gc;
                ushort h = f2bf(acc[r].x);
                oAh[o] = h;
                oAl[o] = f2bf(acc[r].x - bf2f(h));
                ushort h2 = f2bf(acc[r].y);
                oAh[o + 513] = h2;
                oAl[o + 513] = f2bf(acc[r].y - bf2f(h2));
            }
        }
    }
}

// exact sequential recompute of the width-2 border ring (validated R4).
template <int CHAIN>
__global__ __launch_bounds__(256) void k_ring7(
    const float* __restrict__ xr, const float* __restrict__ xi,
    const float* __restrict__ wtr, const float* __restrict__ wti,
    const float* __restrict__ w1r, const float* __restrict__ w1i,
    const float* __restrict__ w2r, const float* __restrict__ w2i,
    const float* __restrict__ w3r, const float* __restrict__ w3i,
    float* __restrict__ outr, float* __restrict__ outi,
    ushort* __restrict__ oAh, ushort* __restrict__ oAl) {
    constexpr bool CPLX = (CHAIN == 1);
    __shared__ float2 W1s[4][9], W2s[16][9], W3s[4][9];
    __shared__ float2 Y[4][4][68];
    __shared__ float2 Z[4][3][66];
    int side = blockIdx.y, b = blockIdx.z;
    int u0 = blockIdx.x * 64;
    int ulo = (side < 2) ? 0 : 2;
    int uhi = (side < 2) ? (NGRID - 1) : (NGRID - 3);
    if (u0 > uhi) return;
    int tid = threadIdx.x;
    const float* rq = xr + (long long)b * NQ;

    for (int idx = tid; idx < 36; idx += 256) {
        int c = idx / 9, s = idx % 9, p = s / 3, q = s % 3;
        if (CHAIN == 0) {
            int i1 = b * 36 + c * 9 + p * 3 + q;
            W1s[c][s] = make_float2(w1r[i1], w1i[i1]);
            W3s[c][s] = make_float2(w3r[i1], w3i[i1]);
        } else {
            int it = b * 36 + c * 9 + q * 3 + p;
            W1s[c][s] = make_float2(w3r[it], -w3i[it]);
            W3s[c][s] = make_float2(w1r[it], -w1i[it]);
        }
    }
    for (int idx = tid; idx < 144; idx += 256) {
        int co = idx / 36, r = idx % 36, ci = r / 9, s = r % 9, p = s / 3, q = s % 3;
        int iw = (CHAIN == 0) ? (b * 144 + co * 36 + ci * 9 + p * 3 + q)
                              : (b * 144 + ci * 36 + co * 9 + q * 3 + p);
        float iv = w2i[iw];
        W2s[co * 4 + ci][s] = make_float2(w2r[iw], (CHAIN == 0) ? iv : -iv);
    }
    __syncthreads();

    for (int idx = tid; idx < 4 * 4 * 68; idx += 256) {
        int ch = idx / (4 * 68), r = idx % (4 * 68), d = r / 68, uu = r % 68;
        int u = u0 - 2 + uu;
        float2 acc = make_float2(0.f, 0.f);
        if (u >= 0 && u < NGRID) {
            int i, j;
            if (side == 0)      { i = d;       j = u; }
            else if (side == 1) { i = 512 - d; j = u; }
            else if (side == 2) { i = u;       j = d; }
            else                { i = u;       j = 512 - d; }
            for (int p = 0; p < 3; ++p)
                for (int q = 0; q < 3; ++q) {
                    int ii = i + p - 1, jj = j + q - 1;
                    if (ii >= 0 && ii < NGRID && jj >= 0 && jj < NGRID) {
                        float vr, vi;
                        if (CHAIN == 0) {
                            vr = rhq_read(rq, ii, jj);
                            vi = 0.0f;
                        } else {
                            long long g = (long long)b * N2G
                                        + (long long)ii * NGRID + jj;
                            float2 sc = scale_wt(xr[g], xi[g], wtr[g], wti[g],
                                                 ii, jj);
                            vr = sc.x; vi = sc.y;
                        }
                        float2 w = W1s[ch][p * 3 + q];
                        acc.x += w.x * vr - w.y * vi;
                        acc.y += w.x * vi + w.y * vr;
                    }
                }
        }
        Y[ch][d][uu] = acc;
    }
    __syncthreads();

    for (int idx = tid; idx < 4 * 3 * 66; idx += 256) {
        int co = idx / (3 * 66), r = idx % (3 * 66), d = r / 66, uu = r % 66;
        int u = u0 - 1 + uu;
        float2 acc = make_float2(0.f, 0.f);
        if (u >= 0 && u < NGRID) {
            for (int p = 0; p < 3; ++p)
                for (int q = 0; q < 3; ++q) {
                    int dd, du;
                    if (side == 0)      { dd = p - 1; du = q - 1; }
                    else if (side == 1) { dd = 1 - p; du = q - 1; }
                    else if (side == 2) { dd = q - 1; du = p - 1; }
                    else                { dd = 1 - q; du = p - 1; }
                    int d2 = d + dd, uy = uu + 1 + du;
                    if (d2 >= 0) {
                        for (int ci = 0; ci < 4; ++ci) {
                            float2 yv = Y[ci][d2][uy];
                            float2 w = W2s[co * 4 + ci][p * 3 + q];
                            acc.x += w.x * yv.x - w.y * yv.y;
                            acc.y += w.x * yv.y + w.y * yv.x;
                        }
                    }
                }
        }
        Z[co][d][uu] = acc;
    }
    __syncthreads();

    for (int idx = tid; idx < 128; idx += 256) {
        int d = idx / 64, uu = idx % 64;
        int u = u0 + uu;
        if (u < ulo || u > uhi) continue;
        float2 acc = make_float2(0.f, 0.f);
        for (int p = 0; p < 3; ++p)
            for (int q = 0; q < 3; ++q) {
                int dd, du;
                if (side == 0)      { dd = p - 1; du = q - 1; }
                else if (side == 1) { dd = 1 - p; du = q - 1; }
                else if (side == 2) { dd = q - 1; du = p - 1; }
                else                { dd = 1 - q; du = p - 1; }
                int d2 = d + dd, uz = uu + 1 + du;
                if (d2 >= 0) {
                    for (int ci = 0; ci < 4; ++ci) {
                        float2 zv = Z[ci][d2][uz];
                        float2 w = W3s[ci][p * 3 + q];
                        acc.x += w.x * zv.x - w.y * zv.y;
                        acc.y += w.x * zv.y + w.y * zv.x;
                    }
                }
            }
        int i, j;
        if (side == 0)      { i = d;       j = u; }
        else if (side == 1) { i = 512 - d; j = u; }
        else if (side == 2) { i = u;       j = d; }
        else                { i = u;       j = 512 - d; }
        if (CHAIN == 0) {
            long long g = (long long)b * N2G + (long long)i * NGRID + j;
            outr[g] = acc.x;
            outi[g] = acc.y;
        } else {
            long long o = (long long)b * 513 * 1056 + (long long)i * 1056 + j;
            ushort h = f2bf(acc.x);
            oAh[o] = h;
            oAl[o] = f2bf(acc.x - bf2f(h));
            ushort h2 = f2bf(acc.y);
            oAh[o + 513] = h2;
            oAl[o + 513] = f2bf(acc.y - bf2f(h2));
        }
    }
}

// ---------------------------------------------------------------------------
// red[2b] += sum(r*e), red[2b+1] += sum((A e)*e), Ae computed inline.
// ---------------------------------------------------------------------------
__global__ void k_dotAe(const float* __restrict__ r, const float* __restrict__ e,
                        const float* __restrict__ a, float* __restrict__ red) {
    int b = blockIdx.y;
    const float* rb = r + (long long)b * N2G;
    const float* eb = e + (long long)b * N2G;
    const float* ab = a + (long long)b * NCELL * NCELL;
    float s1 = 0.0f, s2 = 0.0f;
    for (int idx = blockIdx.x * blockDim.x + threadIdx.x; idx < NI2;
         idx += gridDim.x * blockDim.x) {
        int i = idx / NINT + 1, j = idx % NINT + 1;
        long long g = (long long)i * NGRID + j;
        float ev = eb[g];
        float Ax = darcyA(eb, ab, i, j);
        s1 += rb[g] * ev;
        s2 += Ax * ev;
    }
    #pragma unroll
    for (int o = 32; o > 0; o >>= 1) {
        s1 += __shfl_down(s1, o);
        s2 += __shfl_down(s2, o);
    }
    __shared__ float l1[4], l2[4];
    int wid = threadIdx.x >> 6;
    if ((threadIdx.x & 63) == 0) { l1[wid] = s1; l2[wid] = s2; }
    __syncthreads();
    if (threadIdx.x == 0) {
        atomicAdd(&red[2 * b], l1[0] + l1[1] + l1[2] + l1[3]);
        atomicAdd(&red[2 * b + 1], l2[0] + l2[1] + l2[2] + l2[3]);
    }
}

__global__ void k_update(float* __restrict__ x, const float* __restrict__ e,
                         const float* __restrict__ red) {
    long long idx = (long long)blockIdx.x * blockDim.x + threadIdx.x;
    if (idx >= (long long)NB * N2G) return;
    int b = (int)(idx / N2G);
    float alpha = red[2 * b] / red[2 * b + 1];
    x[idx] += alpha * e[idx];
}

// ---------------------------------------------------------------------------
// final: r = f - A(x + alpha e) fused with norm accumulation.
// ---------------------------------------------------------------------------
__global__ void k_fin(const float* __restrict__ x, const float* __restrict__ e,
                      const float* __restrict__ f, const float* __restrict__ a,
                      float* __restrict__ red) {
    const float c23 = 2.0f / 3.0f, c16 = 1.0f / 6.0f, c13 = 1.0f / 3.0f;
    int b = blockIdx.y;
    long long base = (long long)b * N2G;
    const float* ab = a + (long long)b * NCELL * NCELL;
    float alpha = red[8 + 2 * b] / red[8 + 2 * b + 1];
    float s1 = 0.0f, s2 = 0.0f;
    for (int idx = blockIdx.x * blockDim.x + threadIdx.x; idx < N2G;
         idx += gridDim.x * blockDim.x) {
        int i = idx / NGRID, j = idx - i * NGRID;
        float fv = f[base + idx];
        float rv = fv;
        if (i >= 1 && i <= NINT && j >= 1 && j <= NINT) {
            float a00 = ab[(i - 1) * NCELL + (j - 1)];
            float a01 = ab[(i - 1) * NCELL + j];
            float a10 = ab[i * NCELL + (j - 1)];
            float a11 = ab[i * NCELL + j];
            long long gm = base + (long long)(i - 1) * NGRID + j;
            long long gc = base + (long long)i * NGRID + j;
            long long gp = base + (long long)(i + 1) * NGRID + j;
            float xmm = x[gm - 1] + alpha * e[gm - 1];
            float xm0 = x[gm] + alpha * e[gm];
            float xmp = x[gm + 1] + alpha * e[gm + 1];
            float xcm = x[gc - 1] + alpha * e[gc - 1];
            float xc0 = x[gc] + alpha * e[gc];
            float xcp = x[gc + 1] + alpha * e[gc + 1];
            float xpm = x[gp - 1] + alpha * e[gp - 1];
            float xp0 = x[gp] + alpha * e[gp];
            float xpp = x[gp + 1] + alpha * e[gp + 1];
            float Ax = c23 * (a00 + a01 + a10 + a11) * xc0
                - c16 * ((a00 + a01) * xm0 + (a10 + a11) * xp0
                       + (a00 + a10) * xcm + (a01 + a11) * xcp)
                - c13 * (a00 * xmm + a01 * xmp + a10 * xpm + a11 * xpp);
            rv = fv - Ax;
        }
        s1 += rv * rv;
        s2 += fv * fv;
    }
    #pragma unroll
    for (int o = 32; o > 0; o >>= 1) {
        s1 += __shfl_down(s1, o);
        s2 += __shfl_down(s2, o);
    }
    __shared__ float l1[4], l2[4];
    int wid = threadIdx.x >> 6;
    if ((threadIdx.x & 63) == 0) { l1[wid] = s1; l2[wid] = s2; }
    __syncthreads();
    if (threadIdx.x == 0) {
        atomicAdd(&red[16], l1[0] + l1[1] + l1[2] + l1[3]);
        atomicAdd(&red[17], l2[0] + l2[1] + l2[2] + l2[3]);
    }
}

__global__ void k_final(const float* __restrict__ red, float* __restrict__ out) {
    out[0] = sqrtf(red[16] / red[17]);
}

// ---------------------------------------------------------------------------
extern "C" void kernel_launch(void* const* d_in, const int* in_sizes, int n_in,
                              void* d_out, int out_size, void* d_ws, size_t ws_size,
                              hipStream_t stream) {
    (void)in_sizes; (void)n_in; (void)out_size; (void)ws_size;
    const float* f    = (const float*)d_in[0];
    const float* coef = (const float*)d_in[1];
    const float* w1r  = (const float*)d_in[3];
    const float* w1i  = (const float*)d_in[4];
    const float* w2r  = (const float*)d_in[5];
    const float* w2i  = (const float*)d_in[6];
    const float* w3r  = (const float*)d_in[7];
    const float* w3i  = (const float*)d_in[8];
    const float* wtr  = (const float*)d_in[9];
    const float* wti  = (const float*)d_in[10];
    float* out = (float*)d_out;

    float* ws = (float*)d_ws;
    size_t off = 0;
    auto alloc = [&](long long n) {
        float* p = ws + off;
        off += (size_t)((n + 3) & ~3LL);
        return p;
    };
    float* x0   = alloc((long long)NB * N2G);
    float* x1   = alloc((long long)NB * N2G);
    float* rr   = alloc((long long)NB * N2G);
    float* ee   = alloc((long long)NB * N2G);
    float* dinv = alloc((long long)NB * NI2);
    float* c1r  = alloc((long long)NB * 4 * N2G);
    float* c1i  = alloc((long long)NB * 4 * N2G);
    float* c2r  = alloc((long long)NB * 4 * N2G);
    float* c2i  = alloc((long long)NB * 4 * N2G);
    float* pr   = c1r;  // partial span (c1r..c2i contiguous, ~67 MB)
    float* or_  = alloc((long long)NB * N2G);
    float* oi_  = alloc((long long)NB * N2G);
    float* rhq  = alloc((long long)NB * NQ);   // rh antisym quadrant 257x257
    float* red  = alloc(20);
    ushort* sGh  = (ushort*)alloc(513 * 512 / 2);
    ushort* sGl  = (ushort*)alloc(513 * 512 / 2);
    ushort* sGth = (ushort*)alloc(513 * 512 / 2);
    ushort* sGtl = (ushort*)alloc(513 * 512 / 2);
    ushort* sFAh = (ushort*)alloc(511 * 1056 / 2);
    ushort* sFAl = (ushort*)alloc(511 * 1056 / 2);
    ushort* sFBh = (ushort*)alloc(1022 * 1056 / 2);
    ushort* sFBl = (ushort*)alloc(1022 * 1056 / 2);
    ushort* dA2h = (ushort*)alloc((long long)NB * 257 * 512 / 2);  // gemm2 A
    ushort* dA2l = (ushort*)alloc((long long)NB * 257 * 512 / 2);
    ushort* dA3h = (ushort*)alloc((long long)NB * 513 * 1056 / 2); // gemm3 B
    ushort* dA3l = (ushort*)alloc((long long)NB * 513 * 1056 / 2);
    ushort* dB1h = (ushort*)alloc((long long)NB * 511 * 512 / 2);  // gemm1 B
    ushort* dB1l = (ushort*)alloc((long long)NB * 511 * 512 / 2);
    ushort* dB4h = (ushort*)alloc((long long)NB * 511 * 1056 / 2); // gemm4 B
    ushort* dB4l = (ushort*)alloc((long long)NB * 511 * 1056 / 2);
    float* kcomp = alloc(NB * 2 * 49 * 2);   // composed 7x7 chain kernels
    double* tabD = (double*)alloc(1024 * 2); // sin(pi t/512), t<1024
    double* tabC = (double*)alloc(1026 * 2); // cos(2pi t/1025), t<1025
    double* tabS = (double*)alloc(1026 * 2); // sin(2pi t/1025), t<1025

    dim3 blk2(16, 16);
    dim3 grdS(33, 33, NB);
    dim3 grdC(33, 17, NB);   // conv7: 16x32 output tile per block (R19)
    dim3 grdR(9, 4, NB);     // ring7: 64-wide segments x 4 sides
    const int SP = 4;

    hipMemsetAsync(x0, 0, (size_t)NB * N2G * sizeof(float), stream);
    hipMemsetAsync(ee, 0, (size_t)NB * N2G * sizeof(float), stream);
    hipMemsetAsync(red, 0, 20 * sizeof(float), stream);
    hipMemsetAsync(dA3h, 0, (size_t)NB * 513 * 1056 * 2 * 2, stream);
    hipMemsetAsync(dB1h, 0, (size_t)NB * 511 * 512 * 2 * 2, stream);
    k_tables<<<dim3(5), dim3(256), 0, stream>>>(tabD, tabC, tabS);
    k_genAll<<<dim3((unsigned)((R_TOT + 255) / 256)), dim3(256), 0, stream>>>(
        tabD, tabC, tabS, coef, dinv,
        sGh, sGl, sGth, sGtl, sFAh, sFAl, sFBh, sFBl);
    k_compose<<<dim3(2, NB), dim3(128), 0, stream>>>(w1r, w1i, w2r, w2i, w3r, w3i, kcomp);

    for (int step = 0; step < 2; ++step) {
        // 10 weighted-Jacobi sweeps: x0 -> x1 (5), x1 -> x0 (5 + residual +
        // bf16 transpose planes for gemm1 B)
        k_jacobi5R<0><<<grdS, blk2, 0, stream>>>(
            x0, coef, f, dinv, x1, nullptr, nullptr, nullptr);
        k_jacobi5R<1><<<grdS, blk2, 0, stream>>>(
            x1, coef, f, dinv, x0, rr, dB1h, dB1l);

        // ---- H_apply ----
        // gemm1: t2 = G(257x511) * rI(511x511)   [antisym: M 513 -> 257]
        k_mgemm<<<dim3(4, 3, NB * SP), dim3(256), 0, stream>>>(
            sGh, sGl, 0, dB1h, dB1l, (long long)511 * 512,
            pr, (long long)257 * 511, 257, 511, 512, SP);
        k_redA<<<dim3((257 * 512 + 255) / 256, NB), dim3(256), 0, stream>>>(
            pr, SP, 257, dA2h, dA2l);
        // gemm2: rh_q = t2(257x511) * Gt(511x257) [antisym: N 513 -> 257]
        k_mgemm<<<dim3(3, 3, NB * SP), dim3(256), 0, stream>>>(
            dA2h, dA2l, (long long)257 * 512, sGth, sGtl, 0,
            pr, (long long)NQ, 257, 257, 512, SP);
        k_reduce<<<dim3(259, NB), dim3(256), 0, stream>>>(
            pr, rhq, NQ, 257, 257, (long long)NQ, SP);

        // forward conv chain (rh mirror-read) -> or_/oi_
        k_conv7<0><<<grdC, blk2, 0, stream>>>(
            rhq, nullptr, nullptr, nullptr, kcomp, or_, oi_, nullptr, nullptr);
        k_ring7<0><<<grdR, dim3(256), 0, stream>>>(
            rhq, nullptr, nullptr, nullptr,
            w1r, w1i, w2r, w2i, w3r, w3i, or_, oi_, nullptr, nullptr);
        // adjoint conv chain (fused wt*ik2 scale on load) -> bf16 dA3 planes
        k_conv7<1><<<grdC, blk2, 0, stream>>>(
            or_, oi_, wtr, wti, kcomp, nullptr, nullptr, dA3h, dA3l);
        k_ring7<1><<<grdR, dim3(256), 0, stream>>>(
            or_, oi_, wtr, wti,
            w1r, w1i, w2r, w2i, w3r, w3i, nullptr, nullptr, dA3h, dA3l);

        // gemm3' (transposed): P'[n<1022][m<513] = sFB * dA3^T
        k_mgemm<<<dim3(5, 8, NB * 4), dim3(256), 0, stream>>>(
            sFBh, sFBl, 0, dA3h, dA3l, (long long)513 * 1056,
            pr, 1022LL * 513, 1022, 513, 1056, 4);
        k_redBt<<<dim3(2109, NB), dim3(256), 0, stream>>>(pr, 4, dB4h, dB4l);
        // gemm4: e = [Fr|Fi](511x1026) * [t2r;-t2i](1026x511)
        k_mgemm<<<dim3(4, 4, NB * SP), dim3(256), 0, stream>>>(
            sFAh, sFAl, 0, dB4h, dB4l, (long long)511 * 1056,
            pr, (long long)NI2, 511, 511, 1056, SP);
        k_reduce<<<dim3(1024, NB), dim3(256), 0, stream>>>(
            pr, ee + NGRID + 1, NI2, NINT, NGRID, (long long)N2G, SP);

        // dots (Ae inline); step slots red[8*step ..]
        k_dotAe<<<dim3(128, NB), dim3(256), 0, stream>>>(
            rr, ee, coef, red + 8 * step);
        if (step == 0)
            k_update<<<dim3((NB * N2G + 255) / 256), dim3(256), 0, stream>>>(
                x0, ee, red);
    }
    k_fin<<<dim3(128, NB), dim3(256), 0, stream>>>(x0, ee, f, coef, red);
    k_final<<<dim3(1), dim3(1), 0, stream>>>(red, out);
}